// Round 5
// baseline (385.754 us; speedup 1.0000x reference)
//
#include <hip/hip_runtime.h>

typedef unsigned short u16;
typedef u16  u16x8  __attribute__((ext_vector_type(8)));
typedef _Float16 f16x4 __attribute__((ext_vector_type(4)));
typedef _Float16 f16x8 __attribute__((ext_vector_type(8)));
typedef float f32x4 __attribute__((ext_vector_type(4)));

#define HW 4096
#define CIN 256
#define L2E 1.4426950408889634f

__device__ __forceinline__ float fexp2(float x) { return __builtin_amdgcn_exp2f(x); }

// ---------------- convert x (fp32->fp16) + channel means; convert W ----------------
__global__ __launch_bounds__(256) void convert_kernel(const float* x1, const float* x2, const float* x3,
        const float* W1, const float* W2, const float* W3,
        _Float16* xh, _Float16* wh, float* mean) {
    int bx = blockIdx.x; int t = threadIdx.x;
    if (bx < 1536) {
        int xi = bx >> 9, b = (bx >> 8) & 1, c = bx & 255;
        const float* src = (xi == 0 ? x1 : xi == 1 ? x2 : x3) + (size_t)(b * CIN + c) * HW;
        _Float16* dst = xh + ((size_t)((xi * 2 + b) * CIN) + c) * HW;
        float s = 0.f;
        for (int i = t; i < 1024; i += 256) {
            f32x4 v = ((const f32x4*)src)[i];
            s += v[0] + v[1] + v[2] + v[3];
            f16x4 h;
#pragma unroll
            for (int r = 0; r < 4; ++r) h[r] = (_Float16)v[r];
            ((f16x4*)dst)[i] = h;
        }
        __shared__ float red[256];
        red[t] = s; __syncthreads();
        for (int k = 128; k; k >>= 1) { if (t < k) red[t] += red[t + k]; __syncthreads(); }
        if (t == 0) mean[(xi * 2 + b) * CIN + c] = red[0] * (1.f / HW);
    } else {
        int j = bx - 1536;                 // 0..5
        int widx = j >> 1, half = j & 1;
        const float* wsrc = (widx == 0 ? W1 : widx == 1 ? W2 : W3) + half * 4096;
        _Float16* wdst = wh + widx * 8192 + half * 4096;
        for (int i = t; i < 1024; i += 256) {
            f32x4 v = ((const f32x4*)wsrc)[i];
            f16x4 h;
#pragma unroll
            for (int r = 0; r < 4; ++r) h[r] = (_Float16)v[r];
            ((f16x4*)wdst)[i] = h;
        }
    }
}

// ---------------- M2[x][b][c1][c2] = E_p[x_c1 x_c2] via f16 MFMA ----------------
__global__ __launch_bounds__(256) void m2_kernel(const _Float16* xh, float* M2) {
    int xi = blockIdx.y, b = blockIdx.z;
    const _Float16* xb = xh + (size_t)(xi * 2 + b) * CIN * HW;
    int t = threadIdx.x; int wv = t >> 6; int L = t & 63; int m = L & 15; int quad = L >> 4;
    int tile = blockIdx.x * 4 + wv;            // 0..255
    int c1t = (tile >> 4) * 16, c2t = (tile & 15) * 16;
    const f16x8* ap = (const f16x8*)(xb + (size_t)(c1t + m) * HW + quad * 8);
    const f16x8* bp = (const f16x8*)(xb + (size_t)(c2t + m) * HW + quad * 8);
    f32x4 a0 = {0,0,0,0}, a1 = {0,0,0,0};
#pragma unroll 4
    for (int p = 0; p < 128; p += 2) {
        a0 = __builtin_amdgcn_mfma_f32_16x16x32_f16(ap[p * 4], bp[p * 4], a0, 0, 0, 0);
        a1 = __builtin_amdgcn_mfma_f32_16x16x32_f16(ap[(p + 1) * 4], bp[(p + 1) * 4], a1, 0, 0, 0);
    }
    f32x4 acc = a0 + a1;
    float* dst = M2 + ((size_t)(xi * 2 + b) * CIN) * CIN;
#pragma unroll
    for (int r = 0; r < 4; ++r)
        dst[(size_t)(c1t + quad * 4 + r) * CIN + c2t + m] = acc[r] * (1.f / HW);
}

// ---------------- per-(x,b,o) affine params from stats (q pre-scaled by log2e) ----------------
__global__ __launch_bounds__(256) void stats_kernel(const float* M2, const float* mean,
        const float* W1, const float* W2, const float* W3,
        const float* g1, const float* g2, const float* g3,
        const float* b1, const float* b2, const float* b3, float2* afine) {
    int o = blockIdx.x; int xi = blockIdx.y; int b = blockIdx.z;
    int widx = o >> 5; int oc = o & 31;
    const float* Wp = (widx == 0 ? W1 : widx == 1 ? W2 : W3) + oc * CIN;
    const float* gp = (widx == 0 ? g1 : widx == 1 ? g2 : g3);
    const float* bp = (widx == 0 ? b1 : widx == 1 ? b2 : b3);
    int t = threadIdx.x;
    __shared__ float sW[256];
    __shared__ float red[256];
    sW[t] = Wp[t];
    __syncthreads();
    const float* m2row = M2 + ((size_t)(xi * 2 + b) * CIN + t) * CIN;
    float tv = 0.f;
    const f32x4* r4 = (const f32x4*)m2row;
#pragma unroll 4
    for (int k = 0; k < 64; ++k) {
        f32x4 mv = r4[k];
        const f32x4 wv = *(const f32x4*)&sW[k * 4];
        tv += mv[0] * wv[0] + mv[1] * wv[1] + mv[2] * wv[2] + mv[3] * wv[3];
    }
    red[t] = tv * sW[t]; __syncthreads();
    for (int k = 128; k; k >>= 1) { if (t < k) red[t] += red[t + k]; __syncthreads(); }
    float E2 = red[0]; __syncthreads();
    red[t] = sW[t] * mean[(xi * 2 + b) * CIN + t]; __syncthreads();
    for (int k = 128; k; k >>= 1) { if (t < k) red[t] += red[t + k]; __syncthreads(); }
    if (t == 0) {
        float mu = red[0];
        float var = E2 - mu * mu;
        float rsig = rsqrtf(var + 1e-5f);
        float scale = gp[oc] * rsig;
        float bias = bp[oc] - mu * scale;
        if (widx == 0) { scale *= L2E; bias *= L2E; }   // q carries log2e so S' = S*log2e
        afine[(xi * 2 + b) * 96 + o] = make_float2(scale, bias);
    }
}

// ---- conv + norm + relu: writes qT/kT (fp16, pixel-major) and v (fp32 out) ----
__global__ __launch_bounds__(256) void conv_kernel(const _Float16* xh, const _Float16* wh,
        const float2* afine, _Float16* qT, _Float16* kT, float* out) {
    int xi = blockIdx.y, b = blockIdx.z;
    const u16* xb = (const u16*)(xh + (size_t)(xi * 2 + b) * CIN * HW);
    int p0 = blockIdx.x * 64;
    __shared__ u16 lds[32 * 65 * 8];
    int t = threadIdx.x;
    {   // stage x[256][64] into LDS, transposed to 8-channel cells [cblk][f(p)][8c]
        int pc = t & 7, cg = t >> 3;
        u16x8 a[8];
#pragma unroll
        for (int r = 0; r < 8; ++r)
            a[r] = *(const u16x8*)(xb + (size_t)(cg * 8 + r) * HW + p0 + pc * 8);
#pragma unroll
        for (int i = 0; i < 8; ++i) {
            u16x8 d;
#pragma unroll
            for (int r = 0; r < 8; ++r) d[r] = a[r][i];
            int p = pc * 8 + i; int fp = p ^ (p >> 3);
            *(u16x8*)&lds[(cg * 65 + fp) * 8] = d;
        }
    }
    __syncthreads();
    int wv = t >> 6, L = t & 63, m = L & 15, quad = L >> 4;
    int pw0 = wv * 16;
    f16x8 af[8];
    {
        int p = pw0 + m; int fp = p ^ (p >> 3);
#pragma unroll
        for (int k = 0; k < 8; ++k)
            af[k] = *(const f16x8*)&lds[((k * 4 + quad) * 65 + fp) * 8];
    }
    int xb2 = xi * 2 + b;
    for (int ot = 0; ot < 6; ++ot) {
        int o0 = ot * 16; int widx = ot >> 1;
        int o_col = o0 + m;                         // global output channel 0..95
        f32x4 acc = {0, 0, 0, 0};
#pragma unroll
        for (int k = 0; k < 8; ++k) {
            f16x8 bfr = *(const f16x8*)(wh + (size_t)o_col * CIN + k * 32 + quad * 8);
            acc = __builtin_amdgcn_mfma_f32_16x16x32_f16(af[k], bfr, acc, 0, 0, 0);
        }
        float2 afv = afine[xb2 * 96 + o_col];
        f32x4 vals;
#pragma unroll
        for (int r = 0; r < 4; ++r) {
            float v = acc[r] * afv.x + afv.y;
            vals[r] = v > 0.f ? v : 0.f;
        }
        int prow = p0 + pw0 + quad * 4;
        if (widx < 2) {
            _Float16* dst = (widx == 0 ? qT : kT) + (size_t)xb2 * (HW * 32);
            int cc = (o0 & 31) + m;
#pragma unroll
            for (int r = 0; r < 4; ++r)
                dst[(size_t)(prow + r) * 32 + cc] = (_Float16)vals[r];
        } else {
            float* dst = out + (size_t)(5 + xi) * 262144 + (size_t)b * 131072 + (size_t)(o_col - 64) * HW + prow;
            *(f32x4*)dst = vals;    // fp32 output, 4 consecutive pixels
        }
    }
}

// ---- Z-sweep, j-chunked: per (mat,b,chunk,row) partial (m, l) in log2 domain ----
__global__ __launch_bounds__(256) void zsweep_kernel(const _Float16* qT, const _Float16* kT,
        float2* Pz) {
    const int qxA[5] = {0, 1, 1, 2, 0};   // mats: A12 A21 A23 A32 A13
    const int kxA[5] = {1, 0, 2, 1, 2};
    int mat = blockIdx.y, b = blockIdx.z;
    int qx = qxA[mat], kx = kxA[mat];
    const _Float16* qb = qT + (size_t)(qx * 2 + b) * (HW * 32);
    const _Float16* kb = kT + (size_t)(kx * 2 + b) * (HW * 32);
    int bx = blockIdx.x;                 // 0..255: 64 q-blocks x 4 j-chunks
    int jc = bx & 3, qblk = bx >> 2;
    int t = threadIdx.x; int wv = t >> 6; int L = t & 63; int m = L & 15; int quad = L >> 4;
    int i0 = (qblk * 4 + wv) * 16;
    f16x8 a = *(const f16x8*)(qb + (size_t)(i0 + m) * 32 + quad * 8);
    const f16x8* kp = (const f16x8*)(kb + m * 32 + quad * 8) + (size_t)jc * 64 * 64;
    f32x4 zero = {0.f, 0.f, 0.f, 0.f};
    // phase 1: chunk-local row max (S' >= 0, init 0 exact)
    float mx0 = 0.f, mx1 = 0.f, mx2 = 0.f, mx3 = 0.f;
#pragma unroll 4
    for (int j = 0; j < 64; ++j) {
        f16x8 bf = kp[j * 64];
        f32x4 d = __builtin_amdgcn_mfma_f32_16x16x32_f16(a, bf, zero, 0, 0, 0);
        mx0 = fmaxf(mx0, d[0]); mx1 = fmaxf(mx1, d[1]);
        mx2 = fmaxf(mx2, d[2]); mx3 = fmaxf(mx3, d[3]);
    }
#pragma unroll
    for (int msk = 1; msk <= 8; msk <<= 1) {
        mx0 = fmaxf(mx0, __shfl_xor(mx0, msk)); mx1 = fmaxf(mx1, __shfl_xor(mx1, msk));
        mx2 = fmaxf(mx2, __shfl_xor(mx2, msk)); mx3 = fmaxf(mx3, __shfl_xor(mx3, msk));
    }
    // phase 2: chunk-local l = sum 2^(S'-m)
    float z0 = 0.f, z1 = 0.f, z2 = 0.f, z3 = 0.f;
#pragma unroll 4
    for (int j = 0; j < 64; ++j) {
        f16x8 bf = kp[j * 64];
        f32x4 d = __builtin_amdgcn_mfma_f32_16x16x32_f16(a, bf, zero, 0, 0, 0);
        z0 += fexp2(d[0] - mx0); z1 += fexp2(d[1] - mx1);
        z2 += fexp2(d[2] - mx2); z3 += fexp2(d[3] - mx3);
    }
#pragma unroll
    for (int msk = 1; msk <= 8; msk <<= 1) {
        z0 += __shfl_xor(z0, msk); z1 += __shfl_xor(z1, msk);
        z2 += __shfl_xor(z2, msk); z3 += __shfl_xor(z3, msk);
    }
    if (m == 0) {
        int row = i0 + quad * 4;
        float zz[4] = {z0, z1, z2, z3};
        float mm[4] = {mx0, mx1, mx2, mx3};
#pragma unroll
        for (int r = 0; r < 4; ++r)
            Pz[((size_t)(mat * 2 + b) * 4 + jc) * HW + row + r] = make_float2(mm[r], zz[r]);
    }
}

// ---- combine zsweep partials: M = max m_c, Z = sum l_c * 2^(m_c - M) ----
__global__ __launch_bounds__(256) void zcombine_kernel(const float2* Pz, float* R, float* Mv, float2* Wa) {
    int mb = blockIdx.y;                 // 0..9 = mat*2+b
    int r = blockIdx.x * 256 + threadIdx.x;
    float2 p0 = Pz[((size_t)mb * 4 + 0) * HW + r];
    float2 p1 = Pz[((size_t)mb * 4 + 1) * HW + r];
    float2 p2 = Pz[((size_t)mb * 4 + 2) * HW + r];
    float2 p3 = Pz[((size_t)mb * 4 + 3) * HW + r];
    float M = fmaxf(fmaxf(p0.x, p1.x), fmaxf(p2.x, p3.x));
    float Z = p0.y * fexp2(p0.x - M) + p1.y * fexp2(p1.x - M)
            + p2.y * fexp2(p2.x - M) + p3.y * fexp2(p3.x - M);
    float rz = 1.0f / Z;
    size_t idx = (size_t)mb * HW + r;
    R[idx] = rz; Mv[idx] = M;
    if (mb < 2 || mb >= 8) Wa[idx] = make_float2(rz, 0.f);   // weights for A12 / A13 sweeps
}

// ---- pass2 (unchunked, for the A-pair): out_j = sum_i w_i * 2^(S'_ij - M_i) ----
struct P2Cfg {
    const _Float16* qb; const _Float16* kb;
    const float* Mv;
    const float2* wt;
    float* o1; float* o2;
    const float* rn; float2* wn;
    int wtype;   // -1: none, 0: {rn, o1*rn}
};

__global__ __launch_bounds__(512) void pass2_kernel(P2Cfg c0, P2Cfg c1) {
    P2Cfg c = (blockIdx.y == 0) ? c0 : c1;
    int b = blockIdx.z;
    const _Float16* qb = c.qb + (size_t)b * (HW * 32);
    const _Float16* kb = c.kb + (size_t)b * (HW * 32);
    const float2* wt = c.wt + (size_t)b * HW;
    const float* Mb = c.Mv + (size_t)b * HW;
    int t = threadIdx.x; int wv = t >> 6; int L = t & 63; int m = L & 15; int quad = L >> 4;
    int j0 = blockIdx.x * 16;
    f16x8 bf = *(const f16x8*)(kb + (size_t)(j0 + m) * 32 + quad * 8);
    f32x4 zero = {0.f, 0.f, 0.f, 0.f};
    float a1 = 0.f, a2 = 0.f;
    int ib = wv * 512;
#pragma unroll 2
    for (int tt = 0; tt < 32; ++tt) {
        int i0 = ib + tt * 16;
        f16x8 a = *(const f16x8*)(qb + (size_t)(i0 + m) * 32 + quad * 8);
        f32x4 d = __builtin_amdgcn_mfma_f32_16x16x32_f16(a, bf, zero, 0, 0, 0);
        const float2* wr = wt + i0 + quad * 4;
        f32x4 Mr = *(const f32x4*)(Mb + i0 + quad * 4);
#pragma unroll
        for (int r = 0; r < 4; ++r) {
            float e = fexp2(d[r] - Mr[r]);
            float2 w = wr[r];
            a1 += e * w.x; a2 += e * w.y;
        }
    }
    a1 += __shfl_xor(a1, 16); a1 += __shfl_xor(a1, 32);
    a2 += __shfl_xor(a2, 16); a2 += __shfl_xor(a2, 32);
    __shared__ float2 red[8][16];
    if (L < 16) red[wv][L] = make_float2(a1, a2);
    __syncthreads();
    if (t < 16) {
        float s1 = 0.f, s2 = 0.f;
#pragma unroll
        for (int w = 0; w < 8; ++w) { s1 += red[w][t].x; s2 += red[w][t].y; }
        int jo = b * HW + j0 + t;
        c.o1[jo] = s1; c.o2[jo] = s2;
        if (c.wtype == 0) c.wn[jo] = make_float2(c.rn[jo], s1 * c.rn[jo]);
    }
}

// ---- pass2 i-chunked (x2): writes per-chunk partial (s1,s2); weight-prep done by prep_kernel ----
struct PPCfg {
    const _Float16* qb; const _Float16* kb;
    const float* Mv; const float2* wt; float2* Pp;
};

__global__ __launch_bounds__(512) void pass2p_kernel(PPCfg c) {
    int b = blockIdx.z;
    int bx = blockIdx.x; int jt = bx & 255; int ic = bx >> 8;
    const _Float16* qb = c.qb + (size_t)b * (HW * 32);
    const _Float16* kb = c.kb + (size_t)b * (HW * 32);
    const float2* wt = c.wt + (size_t)b * HW;
    const float* Mb = c.Mv + (size_t)b * HW;
    int t = threadIdx.x; int wv = t >> 6; int L = t & 63; int m = L & 15; int quad = L >> 4;
    int j0 = jt * 16;
    f16x8 bf = *(const f16x8*)(kb + (size_t)(j0 + m) * 32 + quad * 8);
    f32x4 zero = {0.f, 0.f, 0.f, 0.f};
    float a1 = 0.f, a2 = 0.f;
    int ib = ic * 2048 + wv * 256;
#pragma unroll 2
    for (int tt = 0; tt < 16; ++tt) {
        int i0 = ib + tt * 16;
        f16x8 a = *(const f16x8*)(qb + (size_t)(i0 + m) * 32 + quad * 8);
        f32x4 d = __builtin_amdgcn_mfma_f32_16x16x32_f16(a, bf, zero, 0, 0, 0);
        const float2* wr = wt + i0 + quad * 4;
        f32x4 Mr = *(const f32x4*)(Mb + i0 + quad * 4);
#pragma unroll
        for (int r = 0; r < 4; ++r) {
            float e = fexp2(d[r] - Mr[r]);
            float2 w = wr[r];
            a1 += e * w.x; a2 += e * w.y;
        }
    }
    a1 += __shfl_xor(a1, 16); a1 += __shfl_xor(a1, 32);
    a2 += __shfl_xor(a2, 16); a2 += __shfl_xor(a2, 32);
    __shared__ float2 red[8][16];
    if (L < 16) red[wv][L] = make_float2(a1, a2);
    __syncthreads();
    if (t < 16) {
        float s1 = 0.f, s2 = 0.f;
#pragma unroll
        for (int w = 0; w < 8; ++w) { s1 += red[w][t].x; s2 += red[w][t].y; }
        c.Pp[(size_t)(ic * 2 + b) * HW + j0 + t] = make_float2(s1, s2);
    }
}

// ---- combine predecessor partials into next sweep's weight vector ----
__global__ __launch_bounds__(256) void prep_kernel(const float2* Pp, const float* R,
                                                   const float* aux, float2* Wa, int mode) {
    int b = blockIdx.y; int r = blockIdx.x * 256 + threadIdx.x;
    float2 s0 = Pp[(size_t)b * HW + r];
    float2 s1 = Pp[(size_t)(2 + b) * HW + r];
    float sx = s0.x + s1.x, sy = s0.y + s1.y;
    float rn = R[(size_t)b * HW + r];
    float2 w = (mode == 0) ? make_float2(sx * rn, sy * rn)
                           : make_float2(sy * rn, aux[(size_t)b * HW + r] * rn);
    Wa[(size_t)b * HW + r] = w;
}

// ---- broadcast 5 [b,hw] vectors (combining partials) to fp32 [b,32,hw] outputs ----
__global__ __launch_bounds__(256) void bcast_kernel(const float2* PpB, const float2* PpC,
        const float2* PpD, const float* p3b, float* out) {
    int bx = blockIdx.x;              // 0..319
    int s = bx >> 6; int rem = bx & 63; int b = rem >> 5; int c = rem & 31;
    float* dst = out + ((size_t)(s * 2 + b) * 32 + c) * HW;
    int t = threadIdx.x;
#pragma unroll
    for (int k = 0; k < 4; ++k) {
        f32x4 o;
#pragma unroll
        for (int r = 0; r < 4; ++r) {
            int e = k * 1024 + t * 4 + r;
            float val;
            if (s == 0)      val = PpD[(size_t)b * HW + e].x + PpD[(size_t)(2 + b) * HW + e].x;
            else if (s == 1) val = PpD[(size_t)b * HW + e].y + PpD[(size_t)(2 + b) * HW + e].y;
            else if (s == 2) val = PpC[(size_t)b * HW + e].x + PpC[(size_t)(2 + b) * HW + e].x;
            else if (s == 3) val = PpB[(size_t)b * HW + e].y + PpB[(size_t)(2 + b) * HW + e].y;
            else             val = p3b[(size_t)b * HW + e];
            o[r] = val;
        }
        ((f32x4*)dst)[k * 256 + t] = o;
    }
}

extern "C" void kernel_launch(void* const* d_in, const int* in_sizes, int n_in,
                              void* d_out, int out_size, void* d_ws, size_t ws_size,
                              hipStream_t stream) {
    (void)in_sizes; (void)n_in; (void)out_size; (void)ws_size;
    const float* x1 = (const float*)d_in[0];
    const float* x2 = (const float*)d_in[1];
    const float* x3 = (const float*)d_in[2];
    const float* W1 = (const float*)d_in[3];
    const float* g1 = (const float*)d_in[4];
    const float* b1 = (const float*)d_in[5];
    const float* W2 = (const float*)d_in[6];
    const float* g2 = (const float*)d_in[7];
    const float* b2 = (const float*)d_in[8];
    const float* W3 = (const float*)d_in[9];
    const float* g3 = (const float*)d_in[10];
    const float* b3 = (const float*)d_in[11];
    float* out = (float*)d_out;      // reference outputs are float32

    char* w = (char*)d_ws;
    _Float16* xh    = (_Float16*)(w);                    // 12,582,912 B
    _Float16* wh    = (_Float16*)(w + 12582912);         //    49,152 B
    float*    mean  = (float*)(w + 12632064);            //     6,144 B
    float*    M2    = (float*)(w + 12638208);            // 1,572,864 B
    float2*   afine = (float2*)(w + 14211072);           //     4,608 B
    _Float16* qT    = (_Float16*)(w + 14215680);         // 1,572,864 B
    _Float16* kT    = (_Float16*)(w + 15788544);         // 1,572,864 B
    float*    R     = (float*)(w + 17361408);            //   163,840 B
    float*    Mv    = (float*)(w + 17525248);            //   163,840 B
    float2*   Wa    = (float2*)(w + 17689088);           //   327,680 B
    float*    vecs  = (float*)(w + 18016768);            //   294,912 B
    float2*   Pz    = (float2*)(w + 18311680);           // 1,310,720 B
    float2*   PpB   = (float2*)(w + 19622400);           //   131,072 B
    float2*   PpC   = (float2*)(w + 19753472);           //   131,072 B
    float2*   PpD   = (float2*)(w + 19884544);           //   131,072 B

    float* v_c12 = vecs + 0 * 8192;
    float* v_p3b = vecs + 5 * 8192;
    float* v_dmy = vecs + 8 * 8192;

    hipLaunchKernelGGL(convert_kernel, dim3(1542), dim3(256), 0, stream,
                       x1, x2, x3, W1, W2, W3, xh, wh, mean);
    hipLaunchKernelGGL(m2_kernel, dim3(64, 3, 2), dim3(256), 0, stream, xh, M2);
    hipLaunchKernelGGL(stats_kernel, dim3(96, 3, 2), dim3(256), 0, stream,
                       M2, mean, W1, W2, W3, g1, g2, g3, b1, b2, b3, afine);
    hipLaunchKernelGGL(conv_kernel, dim3(64, 3, 2), dim3(256), 0, stream,
                       xh, wh, afine, qT, kT, out);
    hipLaunchKernelGGL(zsweep_kernel, dim3(256, 5, 2), dim3(256), 0, stream, qT, kT, Pz);
    hipLaunchKernelGGL(zcombine_kernel, dim3(16, 10), dim3(256), 0, stream, Pz, R, Mv, Wa);

    // mats: 0:A12(q1,k2) 1:A21(q2,k1) 2:A23(q2,k3) 3:A32(q3,k2) 4:A13(q1,k3)
    P2Cfg cA0 = { qT + 0 * 2 * (HW * 32), kT + 1 * 2 * (HW * 32), Mv + 0 * 2 * HW,
                  Wa + 0 * 8192, v_c12, v_dmy, R + 2 * 8192, Wa + 2 * 8192, 0 };
    P2Cfg cA1 = { qT + 0 * 2 * (HW * 32), kT + 2 * 2 * (HW * 32), Mv + 4 * 2 * HW,
                  Wa + 4 * 8192, v_p3b, v_dmy, nullptr, nullptr, -1 };
    hipLaunchKernelGGL(pass2_kernel, dim3(256, 2, 2), dim3(512), 0, stream, cA0, cA1);

    PPCfg cB = { qT + 1 * 2 * (HW * 32), kT + 2 * 2 * (HW * 32), Mv + 2 * 2 * HW,
                 Wa + 2 * 8192, PpB };
    hipLaunchKernelGGL(pass2p_kernel, dim3(512, 1, 2), dim3(512), 0, stream, cB);
    hipLaunchKernelGGL(prep_kernel, dim3(16, 2), dim3(256), 0, stream,
                       PpB, R + 3 * 8192, (const float*)nullptr, Wa + 3 * 8192, 0);

    PPCfg cC = { qT + 2 * 2 * (HW * 32), kT + 1 * 2 * (HW * 32), Mv + 3 * 2 * HW,
                 Wa + 3 * 8192, PpC };
    hipLaunchKernelGGL(pass2p_kernel, dim3(512, 1, 2), dim3(512), 0, stream, cC);
    hipLaunchKernelGGL(prep_kernel, dim3(16, 2), dim3(256), 0, stream,
                       PpC, R + 1 * 8192, v_c12, Wa + 1 * 8192, 1);

    PPCfg cD = { qT + 1 * 2 * (HW * 32), kT + 0 * 2 * (HW * 32), Mv + 1 * 2 * HW,
                 Wa + 1 * 8192, PpD };
    hipLaunchKernelGGL(pass2p_kernel, dim3(512, 1, 2), dim3(512), 0, stream, cD);

    hipLaunchKernelGGL(bcast_kernel, dim3(320), dim3(256), 0, stream, PpB, PpC, PpD, v_p3b, out);
}

// Round 6
// 320.741 us; speedup vs baseline: 1.2027x; 1.2027x over previous
//
#include <hip/hip_runtime.h>

typedef unsigned short u16;
typedef u16  u16x8  __attribute__((ext_vector_type(8)));
typedef _Float16 f16x4 __attribute__((ext_vector_type(4)));
typedef _Float16 f16x8 __attribute__((ext_vector_type(8)));
typedef float f32x4 __attribute__((ext_vector_type(4)));

#define HW 4096
#define CIN 256
#define HW32 (HW * 32)
#define L2E 1.4426950408889634f

__device__ __forceinline__ float fexp2(float x) { return __builtin_amdgcn_exp2f(x); }

// ---------------- convert x (fp32->fp16) + channel means; convert W ----------------
__global__ __launch_bounds__(256) void convert_kernel(const float* x1, const float* x2, const float* x3,
        const float* W1, const float* W2, const float* W3,
        _Float16* xh, _Float16* wh, float* mean) {
    int bx = blockIdx.x; int t = threadIdx.x;
    if (bx < 1536) {
        int xi = bx >> 9, b = (bx >> 8) & 1, c = bx & 255;
        const float* src = (xi == 0 ? x1 : xi == 1 ? x2 : x3) + (size_t)(b * CIN + c) * HW;
        _Float16* dst = xh + ((size_t)((xi * 2 + b) * CIN) + c) * HW;
        float s = 0.f;
        for (int i = t; i < 1024; i += 256) {
            f32x4 v = ((const f32x4*)src)[i];
            s += v[0] + v[1] + v[2] + v[3];
            f16x4 h;
#pragma unroll
            for (int r = 0; r < 4; ++r) h[r] = (_Float16)v[r];
            ((f16x4*)dst)[i] = h;
        }
        __shared__ float red[256];
        red[t] = s; __syncthreads();
        for (int k = 128; k; k >>= 1) { if (t < k) red[t] += red[t + k]; __syncthreads(); }
        if (t == 0) mean[(xi * 2 + b) * CIN + c] = red[0] * (1.f / HW);
    } else {
        int j = bx - 1536;                 // 0..5
        int widx = j >> 1, half = j & 1;
        const float* wsrc = (widx == 0 ? W1 : widx == 1 ? W2 : W3) + half * 4096;
        _Float16* wdst = wh + widx * 8192 + half * 4096;
        for (int i = t; i < 1024; i += 256) {
            f32x4 v = ((const f32x4*)wsrc)[i];
            f16x4 h;
#pragma unroll
            for (int r = 0; r < 4; ++r) h[r] = (_Float16)v[r];
            ((f16x4*)wdst)[i] = h;
        }
    }
}

// ---------------- M2[x][b][c1][c2] = E_p[x_c1 x_c2] via f16 MFMA ----------------
__global__ __launch_bounds__(256) void m2_kernel(const _Float16* xh, float* M2) {
    int xi = blockIdx.y, b = blockIdx.z;
    const _Float16* xb = xh + (size_t)(xi * 2 + b) * CIN * HW;
    int t = threadIdx.x; int wv = t >> 6; int L = t & 63; int m = L & 15; int quad = L >> 4;
    int tile = blockIdx.x * 4 + wv;            // 0..255
    int c1t = (tile >> 4) * 16, c2t = (tile & 15) * 16;
    const f16x8* ap = (const f16x8*)(xb + (size_t)(c1t + m) * HW + quad * 8);
    const f16x8* bp = (const f16x8*)(xb + (size_t)(c2t + m) * HW + quad * 8);
    f32x4 a0 = {0,0,0,0}, a1 = {0,0,0,0};
#pragma unroll 4
    for (int p = 0; p < 128; p += 2) {
        a0 = __builtin_amdgcn_mfma_f32_16x16x32_f16(ap[p * 4], bp[p * 4], a0, 0, 0, 0);
        a1 = __builtin_amdgcn_mfma_f32_16x16x32_f16(ap[(p + 1) * 4], bp[(p + 1) * 4], a1, 0, 0, 0);
    }
    f32x4 acc = a0 + a1;
    float* dst = M2 + ((size_t)(xi * 2 + b) * CIN) * CIN;
#pragma unroll
    for (int r = 0; r < 4; ++r)
        dst[(size_t)(c1t + quad * 4 + r) * CIN + c2t + m] = acc[r] * (1.f / HW);
}

// ---------------- per-(x,b,o) affine params from stats (q pre-scaled by log2e) ----------------
__global__ __launch_bounds__(256) void stats_kernel(const float* M2, const float* mean,
        const float* W1, const float* W2, const float* W3,
        const float* g1, const float* g2, const float* g3,
        const float* b1, const float* b2, const float* b3, float2* afine) {
    int o = blockIdx.x; int xi = blockIdx.y; int b = blockIdx.z;
    int widx = o >> 5; int oc = o & 31;
    const float* Wp = (widx == 0 ? W1 : widx == 1 ? W2 : W3) + oc * CIN;
    const float* gp = (widx == 0 ? g1 : widx == 1 ? g2 : g3);
    const float* bp = (widx == 0 ? b1 : widx == 1 ? b2 : b3);
    int t = threadIdx.x;
    __shared__ float sW[256];
    __shared__ float red[256];
    sW[t] = Wp[t];
    __syncthreads();
    const float* m2row = M2 + ((size_t)(xi * 2 + b) * CIN + t) * CIN;
    float tv = 0.f;
    const f32x4* r4 = (const f32x4*)m2row;
#pragma unroll 4
    for (int k = 0; k < 64; ++k) {
        f32x4 mv = r4[k];
        const f32x4 wv = *(const f32x4*)&sW[k * 4];
        tv += mv[0] * wv[0] + mv[1] * wv[1] + mv[2] * wv[2] + mv[3] * wv[3];
    }
    red[t] = tv * sW[t]; __syncthreads();
    for (int k = 128; k; k >>= 1) { if (t < k) red[t] += red[t + k]; __syncthreads(); }
    float E2 = red[0]; __syncthreads();
    red[t] = sW[t] * mean[(xi * 2 + b) * CIN + t]; __syncthreads();
    for (int k = 128; k; k >>= 1) { if (t < k) red[t] += red[t + k]; __syncthreads(); }
    if (t == 0) {
        float mu = red[0];
        float var = E2 - mu * mu;
        float rsig = rsqrtf(var + 1e-5f);
        float scale = gp[oc] * rsig;
        float bias = bp[oc] - mu * scale;
        if (widx == 0) { scale *= L2E; bias *= L2E; }   // q carries log2e so S' = S*log2e
        afine[(xi * 2 + b) * 96 + o] = make_float2(scale, bias);
    }
}

// ---- conv + norm + relu: writes qT/kT (fp16, pixel-major) and v (fp32 out) ----
__global__ __launch_bounds__(256) void conv_kernel(const _Float16* xh, const _Float16* wh,
        const float2* afine, _Float16* qT, _Float16* kT, float* out) {
    int xi = blockIdx.y, b = blockIdx.z;
    const u16* xb = (const u16*)(xh + (size_t)(xi * 2 + b) * CIN * HW);
    int p0 = blockIdx.x * 64;
    __shared__ u16 lds[32 * 65 * 8];
    int t = threadIdx.x;
    {   // stage x[256][64] into LDS, transposed to 8-channel cells [cblk][f(p)][8c]
        int pc = t & 7, cg = t >> 3;
        u16x8 a[8];
#pragma unroll
        for (int r = 0; r < 8; ++r)
            a[r] = *(const u16x8*)(xb + (size_t)(cg * 8 + r) * HW + p0 + pc * 8);
#pragma unroll
        for (int i = 0; i < 8; ++i) {
            u16x8 d;
#pragma unroll
            for (int r = 0; r < 8; ++r) d[r] = a[r][i];
            int p = pc * 8 + i; int fp = p ^ (p >> 3);
            *(u16x8*)&lds[(cg * 65 + fp) * 8] = d;
        }
    }
    __syncthreads();
    int wv = t >> 6, L = t & 63, m = L & 15, quad = L >> 4;
    int pw0 = wv * 16;
    f16x8 af[8];
    {
        int p = pw0 + m; int fp = p ^ (p >> 3);
#pragma unroll
        for (int k = 0; k < 8; ++k)
            af[k] = *(const f16x8*)&lds[((k * 4 + quad) * 65 + fp) * 8];
    }
    int xb2 = xi * 2 + b;
    for (int ot = 0; ot < 6; ++ot) {
        int o0 = ot * 16; int widx = ot >> 1;
        int o_col = o0 + m;                         // global output channel 0..95
        f32x4 acc = {0, 0, 0, 0};
#pragma unroll
        for (int k = 0; k < 8; ++k) {
            f16x8 bfr = *(const f16x8*)(wh + (size_t)o_col * CIN + k * 32 + quad * 8);
            acc = __builtin_amdgcn_mfma_f32_16x16x32_f16(af[k], bfr, acc, 0, 0, 0);
        }
        float2 afv = afine[xb2 * 96 + o_col];
        f32x4 vals;
#pragma unroll
        for (int r = 0; r < 4; ++r) {
            float v = acc[r] * afv.x + afv.y;
            vals[r] = v > 0.f ? v : 0.f;
        }
        int prow = p0 + pw0 + quad * 4;
        if (widx < 2) {
            _Float16* dst = (widx == 0 ? qT : kT) + (size_t)xb2 * HW32;
            int cc = (o0 & 31) + m;
#pragma unroll
            for (int r = 0; r < 4; ++r)
                dst[(size_t)(prow + r) * 32 + cc] = (_Float16)vals[r];
        } else {
            float* dst = out + (size_t)(5 + xi) * 262144 + (size_t)b * 131072 + (size_t)(o_col - 64) * HW + prow;
            *(f32x4*)dst = vals;    // fp32 output, 4 consecutive pixels
        }
    }
}

// ---- Z-sweep: 4 q-tiles/wave, 16 j-chunks; partial (m,l) per (mat,b,chunk,row) ----
__global__ __launch_bounds__(256) void zsweep_kernel(const _Float16* qT, const _Float16* kT,
        float2* Pz) {
    const int qxA[5] = {0, 1, 1, 2, 0};   // mats: A12 A21 A23 A32 A13
    const int kxA[5] = {1, 0, 2, 1, 2};
    int mat = blockIdx.y, b = blockIdx.z;
    const _Float16* qb = qT + (size_t)(qxA[mat] * 2 + b) * HW32;
    const _Float16* kb = kT + (size_t)(kxA[mat] * 2 + b) * HW32;
    int bx = blockIdx.x;                 // 16 qblk x 16 jc
    int jc = bx & 15, qblk = bx >> 4;
    int t = threadIdx.x; int wv = t >> 6; int L = t & 63; int m = L & 15; int quad = L >> 4;
    int i0 = qblk * 256 + wv * 64;       // wave covers 64 q rows (4 tiles)
    f16x8 a[4];
#pragma unroll
    for (int tt = 0; tt < 4; ++tt)
        a[tt] = *(const f16x8*)(qb + (size_t)(i0 + tt * 16 + m) * 32 + quad * 8);
    const f16x8* kp = (const f16x8*)(kb + m * 32 + quad * 8) + (size_t)jc * (16 * 64);
    f32x4 zero = {0.f, 0.f, 0.f, 0.f};
    f32x4 mx[4] = {zero, zero, zero, zero};
#pragma unroll 4
    for (int j = 0; j < 16; ++j) {
        f16x8 bf = kp[j * 64];
#pragma unroll
        for (int tt = 0; tt < 4; ++tt) {
            f32x4 d = __builtin_amdgcn_mfma_f32_16x16x32_f16(a[tt], bf, zero, 0, 0, 0);
            mx[tt][0] = fmaxf(mx[tt][0], d[0]); mx[tt][1] = fmaxf(mx[tt][1], d[1]);
            mx[tt][2] = fmaxf(mx[tt][2], d[2]); mx[tt][3] = fmaxf(mx[tt][3], d[3]);
        }
    }
#pragma unroll
    for (int tt = 0; tt < 4; ++tt)
#pragma unroll
        for (int msk = 1; msk <= 8; msk <<= 1) {
            mx[tt][0] = fmaxf(mx[tt][0], __shfl_xor(mx[tt][0], msk));
            mx[tt][1] = fmaxf(mx[tt][1], __shfl_xor(mx[tt][1], msk));
            mx[tt][2] = fmaxf(mx[tt][2], __shfl_xor(mx[tt][2], msk));
            mx[tt][3] = fmaxf(mx[tt][3], __shfl_xor(mx[tt][3], msk));
        }
    f32x4 neg[4];
#pragma unroll
    for (int tt = 0; tt < 4; ++tt) neg[tt] = -mx[tt];
    f32x4 z[4] = {zero, zero, zero, zero};
#pragma unroll 4
    for (int j = 0; j < 16; ++j) {
        f16x8 bf = kp[j * 64];
#pragma unroll
        for (int tt = 0; tt < 4; ++tt) {
            f32x4 d = __builtin_amdgcn_mfma_f32_16x16x32_f16(a[tt], bf, neg[tt], 0, 0, 0);
            z[tt][0] += fexp2(d[0]); z[tt][1] += fexp2(d[1]);
            z[tt][2] += fexp2(d[2]); z[tt][3] += fexp2(d[3]);
        }
    }
#pragma unroll
    for (int tt = 0; tt < 4; ++tt)
#pragma unroll
        for (int msk = 1; msk <= 8; msk <<= 1) {
            z[tt][0] += __shfl_xor(z[tt][0], msk); z[tt][1] += __shfl_xor(z[tt][1], msk);
            z[tt][2] += __shfl_xor(z[tt][2], msk); z[tt][3] += __shfl_xor(z[tt][3], msk);
        }
    if (m == 0) {
        int mb = mat * 2 + b;
#pragma unroll
        for (int tt = 0; tt < 4; ++tt) {
            int row = i0 + tt * 16 + quad * 4;
#pragma unroll
            for (int r = 0; r < 4; ++r)
                Pz[((size_t)mb * 16 + jc) * HW + row + r] = make_float2(mx[tt][r], z[tt][r]);
        }
    }
}

// ---- combine zsweep partials: M = max m_c, Z = sum l_c * 2^(m_c - M) ----
__global__ __launch_bounds__(256) void zcombine_kernel(const float2* Pz, float* R, float* Mv, float2* Wa) {
    int mb = blockIdx.y;                 // 0..9 = mat*2+b
    int r = blockIdx.x * 256 + threadIdx.x;
    float2 p[16];
    float M = 0.f;
#pragma unroll
    for (int c = 0; c < 16; ++c) {
        p[c] = Pz[((size_t)mb * 16 + c) * HW + r];
        M = fmaxf(M, p[c].x);
    }
    float Z = 0.f;
#pragma unroll
    for (int c = 0; c < 16; ++c) Z += p[c].y * fexp2(p[c].x - M);
    float rz = 1.0f / Z;
    size_t idx = (size_t)mb * HW + r;
    R[idx] = rz; Mv[idx] = M;
    if (mb < 2 || mb >= 8) Wa[idx] = make_float2(rz, 0.f);   // weights for A12 / A13 sweeps
}

// ---- pass2, i-chunked, 4 j-tiles/wave: partial (s1,s2)[ic][b][j] ----
struct PCfg {
    const _Float16* qb; const _Float16* kb;   // bases covering 2 batches
    const float* Mv;                          // [2][HW] row maxes
    const float2* wt;                         // [2][HW] weights per i
    float2* Pp;                               // [(ic*2+b)*HW + j]
    int nit;                                  // i-iters per chunk (chunk = nit*16 rows)
};

__global__ __launch_bounds__(256) void pass2p_kernel(PCfg c0, PCfg c1) {
    PCfg c = (blockIdx.y == 0) ? c0 : c1;
    int b = blockIdx.z;
    int bx = blockIdx.x; int jb = bx & 15; int ic = bx >> 4;
    const _Float16* qb = c.qb + (size_t)b * HW32;
    const _Float16* kb = c.kb + (size_t)b * HW32;
    const float2* wt = c.wt + (size_t)b * HW;
    const float* Mb = c.Mv + (size_t)b * HW;
    int t = threadIdx.x; int wv = t >> 6; int L = t & 63; int m = L & 15; int quad = L >> 4;
    int j0 = jb * 256 + wv * 64;         // wave covers 64 j columns (4 tiles)
    f16x8 bf[4];
#pragma unroll
    for (int tt = 0; tt < 4; ++tt)
        bf[tt] = *(const f16x8*)(kb + (size_t)(j0 + tt * 16 + m) * 32 + quad * 8);
    float a1[4] = {0, 0, 0, 0}, a2[4] = {0, 0, 0, 0};
    int ibase = ic * (c.nit * 16);
#pragma unroll 4
    for (int it = 0; it < c.nit; ++it) {
        int i0 = ibase + it * 16;
        f16x8 av = *(const f16x8*)(qb + (size_t)(i0 + m) * 32 + quad * 8);
        f32x4 Mr = *(const f32x4*)(Mb + i0 + quad * 4);
        f32x4 negM = -Mr;
        const float2* wr = wt + i0 + quad * 4;
        float2 w0 = wr[0], w1 = wr[1], w2 = wr[2], w3 = wr[3];
#pragma unroll
        for (int tt = 0; tt < 4; ++tt) {
            f32x4 d = __builtin_amdgcn_mfma_f32_16x16x32_f16(av, bf[tt], negM, 0, 0, 0);
            float e0 = fexp2(d[0]), e1 = fexp2(d[1]), e2 = fexp2(d[2]), e3 = fexp2(d[3]);
            a1[tt] += e0 * w0.x + e1 * w1.x + e2 * w2.x + e3 * w3.x;
            a2[tt] += e0 * w0.y + e1 * w1.y + e2 * w2.y + e3 * w3.y;
        }
    }
#pragma unroll
    for (int tt = 0; tt < 4; ++tt) {
        a1[tt] += __shfl_xor(a1[tt], 16); a1[tt] += __shfl_xor(a1[tt], 32);
        a2[tt] += __shfl_xor(a2[tt], 16); a2[tt] += __shfl_xor(a2[tt], 32);
    }
    if (quad == 0) {
        float2* dst = c.Pp + ((size_t)ic * 2 + b) * HW;
#pragma unroll
        for (int tt = 0; tt < 4; ++tt)
            dst[j0 + tt * 16 + m] = make_float2(a1[tt], a2[tt]);
    }
}

// ---- prepA: combine A12/A13 partials -> c12, c13(p3b); build A23 weights ----
__global__ __launch_bounds__(256) void prepA_kernel(const float2* PpA, const float* R,
        float* c12, float* c13, float2* Wa2) {
    int b = blockIdx.y; int j = blockIdx.x * 256 + threadIdx.x;
    float s12 = 0.f, s13 = 0.f;
    for (int ic = 0; ic < 16; ++ic) {
        s12 += PpA[((size_t)ic * 2 + b) * HW + j].x;
        s13 += PpA[((size_t)(16 + ic) * 2 + b) * HW + j].x;
    }
    c12[(size_t)b * HW + j] = s12; c13[(size_t)b * HW + j] = s13;
    float rn = R[((size_t)(2 * 2 + b)) * HW + j];     // 1/Z for A23
    Wa2[(size_t)b * HW + j] = make_float2(rn, s12 * rn);
}

// ---- prep: combine IC partials -> o1,o2; build next weights ----
__global__ __launch_bounds__(256) void prep_kernel(const float2* Pp, const float* Rn,
        const float* aux, float* o1, float* o2, float2* Wn, int IC, int mode) {
    int b = blockIdx.y; int j = blockIdx.x * 256 + threadIdx.x;
    float s1 = 0.f, s2 = 0.f;
    for (int ic = 0; ic < IC; ++ic) {
        float2 p = Pp[((size_t)ic * 2 + b) * HW + j];
        s1 += p.x; s2 += p.y;
    }
    if (o1) o1[(size_t)b * HW + j] = s1;
    if (o2) o2[(size_t)b * HW + j] = s2;
    if (Wn) {
        float rn = Rn[(size_t)b * HW + j];
        float2 w = (mode == 0) ? make_float2(s1 * rn, s2 * rn)
                               : make_float2(s2 * rn, aux[(size_t)b * HW + j] * rn);
        Wn[(size_t)b * HW + j] = w;
    }
}

// ---- broadcast 5 [b,hw] vectors to fp32 [b,32,hw] outputs ----
__global__ __launch_bounds__(256) void bcast_kernel(const float* vecs, float* out) {
    int bx = blockIdx.x;              // 0..319
    int s = bx >> 6; int rem = bx & 63; int b = rem >> 5; int c = rem & 31;
    const float* src = vecs + ((size_t)s * 2 + b) * HW;   // slots 0..4 in output order
    float* dst = out + ((size_t)(s * 2 + b) * 32 + c) * HW;
    int t = threadIdx.x;
#pragma unroll
    for (int k = 0; k < 4; ++k)
        ((f32x4*)dst)[k * 256 + t] = ((const f32x4*)src)[k * 256 + t];
}

extern "C" void kernel_launch(void* const* d_in, const int* in_sizes, int n_in,
                              void* d_out, int out_size, void* d_ws, size_t ws_size,
                              hipStream_t stream) {
    (void)in_sizes; (void)n_in; (void)out_size; (void)ws_size;
    const float* x1 = (const float*)d_in[0];
    const float* x2 = (const float*)d_in[1];
    const float* x3 = (const float*)d_in[2];
    const float* W1 = (const float*)d_in[3];
    const float* g1 = (const float*)d_in[4];
    const float* b1 = (const float*)d_in[5];
    const float* W2 = (const float*)d_in[6];
    const float* g2 = (const float*)d_in[7];
    const float* b2 = (const float*)d_in[8];
    const float* W3 = (const float*)d_in[9];
    const float* g3 = (const float*)d_in[10];
    const float* b3 = (const float*)d_in[11];
    float* out = (float*)d_out;      // reference outputs are float32

    char* w = (char*)d_ws;
    _Float16* xh    = (_Float16*)(w);                    // 12,582,912
    _Float16* wh    = (_Float16*)(w + 12582912);         //     49,152
    float*    mean  = (float*)(w + 12632064);            //      6,144
    float*    M2    = (float*)(w + 12638208);            //  1,572,864
    float2*   afine = (float2*)(w + 14211072);           //      4,608
    _Float16* qT    = (_Float16*)(w + 14215680);         //  1,572,864
    _Float16* kT    = (_Float16*)(w + 15788544);         //  1,572,864
    float*    R     = (float*)(w + 17361408);            //    163,840
    float*    Mv    = (float*)(w + 17525248);            //    163,840
    float2*   Wa    = (float2*)(w + 17689088);           //    327,680
    float*    vecs  = (float*)(w + 18016768);            //    196,608 (6 slots x 2 x HW)
    float2*   Pz    = (float2*)(w + 18213376);           //  5,242,880
    float2*   PpA   = (float2*)(w + 23456256);           //  2,097,152
    float2*   PpB   = (float2*)(w + 25553408);           //  2,097,152
    float2*   PpC   = (float2*)(w + 27650560);           //  2,097,152
    float2*   PpD   = (float2*)(w + 29747712);           //  2,097,152

    float* v_p1a = vecs + 0 * 2 * HW;
    float* v_p1b = vecs + 1 * 2 * HW;
    float* v_p2  = vecs + 2 * 2 * HW;
    float* v_p3a = vecs + 3 * 2 * HW;
    float* v_p3b = vecs + 4 * 2 * HW;   // c13
    float* v_c12 = vecs + 5 * 2 * HW;

    hipLaunchKernelGGL(convert_kernel, dim3(1542), dim3(256), 0, stream,
                       x1, x2, x3, W1, W2, W3, xh, wh, mean);
    hipLaunchKernelGGL(m2_kernel, dim3(64, 3, 2), dim3(256), 0, stream, xh, M2);
    hipLaunchKernelGGL(stats_kernel, dim3(96, 3, 2), dim3(256), 0, stream,
                       M2, mean, W1, W2, W3, g1, g2, g3, b1, b2, b3, afine);
    hipLaunchKernelGGL(conv_kernel, dim3(64, 3, 2), dim3(256), 0, stream,
                       xh, wh, afine, qT, kT, out);
    hipLaunchKernelGGL(zsweep_kernel, dim3(256, 5, 2), dim3(256), 0, stream, qT, kT, Pz);
    hipLaunchKernelGGL(zcombine_kernel, dim3(16, 10), dim3(256), 0, stream, Pz, R, Mv, Wa);

    // mats: 0:A12(q1,k2) 1:A21(q2,k1) 2:A23(q2,k3) 3:A32(q3,k2) 4:A13(q1,k3)
    // A-pair: A12 and A13 with w = {1/Z, 0}; IC=16 (nit=16)
    PCfg cA0 = { qT + 0 * 2 * HW32, kT + 1 * 2 * HW32, Mv + 0 * 2 * HW, Wa + 0 * 2 * HW, PpA,               16 };
    PCfg cA1 = { qT + 0 * 2 * HW32, kT + 2 * 2 * HW32, Mv + 4 * 2 * HW, Wa + 4 * 2 * HW, PpA + 16 * 2 * HW, 16 };
    hipLaunchKernelGGL(pass2p_kernel, dim3(256, 2, 2), dim3(256), 0, stream, cA0, cA1);
    hipLaunchKernelGGL(prepA_kernel, dim3(16, 2), dim3(256), 0, stream,
                       PpA, R, v_c12, v_p3b, Wa + 2 * 2 * HW);

    // B: A23 sweep (q2,k3), w = {rn23, c12*rn23} -> o1=c23, o2=u1(p3a); IC=32 (nit=8)
    PCfg cB = { qT + 1 * 2 * HW32, kT + 2 * 2 * HW32, Mv + 2 * 2 * HW, Wa + 2 * 2 * HW, PpB, 8 };
    hipLaunchKernelGGL(pass2p_kernel, dim3(512, 1, 2), dim3(256), 0, stream, cB, cB);
    hipLaunchKernelGGL(prep_kernel, dim3(16, 2), dim3(256), 0, stream,
                       PpB, R + 3 * 2 * HW, (const float*)nullptr,
                       (float*)nullptr, v_p3a, Wa + 3 * 2 * HW, 32, 0);

    // C: A32 sweep (q3,k2), w = {c23*rn32, u1*rn32} -> o1=p2, o2=u2; IC=32
    PCfg cC = { qT + 2 * 2 * HW32, kT + 1 * 2 * HW32, Mv + 3 * 2 * HW, Wa + 3 * 2 * HW, PpC, 8 };
    hipLaunchKernelGGL(pass2p_kernel, dim3(512, 1, 2), dim3(256), 0, stream, cC, cC);
    hipLaunchKernelGGL(prep_kernel, dim3(16, 2), dim3(256), 0, stream,
                       PpC, R + 1 * 2 * HW, v_c12,
                       v_p2, (float*)nullptr, Wa + 1 * 2 * HW, 32, 1);

    // D: A21 sweep (q2,k1), w = {u2*rn21, c12*rn21} -> o1=p1a, o2=p1b; IC=32
    PCfg cD = { qT + 1 * 2 * HW32, kT + 0 * 2 * HW32, Mv + 1 * 2 * HW, Wa + 1 * 2 * HW, PpD, 8 };
    hipLaunchKernelGGL(pass2p_kernel, dim3(512, 1, 2), dim3(256), 0, stream, cD, cD);
    hipLaunchKernelGGL(prep_kernel, dim3(16, 2), dim3(256), 0, stream,
                       PpD, (const float*)nullptr, (const float*)nullptr,
                       v_p1a, v_p1b, (float2*)nullptr, 32, 0);

    hipLaunchKernelGGL(bcast_kernel, dim3(320), dim3(256), 0, stream, vecs, out);
}

// Round 7
// 293.270 us; speedup vs baseline: 1.3154x; 1.0937x over previous
//
#include <hip/hip_runtime.h>

typedef unsigned short u16;
typedef u16  u16x8  __attribute__((ext_vector_type(8)));
typedef _Float16 f16x4 __attribute__((ext_vector_type(4)));
typedef _Float16 f16x8 __attribute__((ext_vector_type(8)));
typedef float f32x4 __attribute__((ext_vector_type(4)));

#define HW 4096
#define CIN 256
#define HW32 (HW * 32)
#define L2E 1.4426950408889634f

__device__ __forceinline__ float fexp2(float x) { return __builtin_amdgcn_exp2f(x); }

// ---------------- convert x (fp32->fp16) + channel means; convert W ----------------
__global__ __launch_bounds__(256) void convert_kernel(const float* x1, const float* x2, const float* x3,
        const float* W1, const float* W2, const float* W3,
        _Float16* xh, _Float16* wh, float* mean) {
    int bx = blockIdx.x; int t = threadIdx.x;
    if (bx < 1536) {
        int xi = bx >> 9, b = (bx >> 8) & 1, c = bx & 255;
        const float* src = (xi == 0 ? x1 : xi == 1 ? x2 : x3) + (size_t)(b * CIN + c) * HW;
        _Float16* dst = xh + ((size_t)((xi * 2 + b) * CIN) + c) * HW;
        float s = 0.f;
        for (int i = t; i < 1024; i += 256) {
            f32x4 v = ((const f32x4*)src)[i];
            s += v[0] + v[1] + v[2] + v[3];
            f16x4 h;
#pragma unroll
            for (int r = 0; r < 4; ++r) h[r] = (_Float16)v[r];
            ((f16x4*)dst)[i] = h;
        }
        __shared__ float red[256];
        red[t] = s; __syncthreads();
        for (int k = 128; k; k >>= 1) { if (t < k) red[t] += red[t + k]; __syncthreads(); }
        if (t == 0) mean[(xi * 2 + b) * CIN + c] = red[0] * (1.f / HW);
    } else {
        int j = bx - 1536;                 // 0..5
        int widx = j >> 1, half = j & 1;
        const float* wsrc = (widx == 0 ? W1 : widx == 1 ? W2 : W3) + half * 4096;
        _Float16* wdst = wh + widx * 8192 + half * 4096;
        for (int i = t; i < 1024; i += 256) {
            f32x4 v = ((const f32x4*)wsrc)[i];
            f16x4 h;
#pragma unroll
            for (int r = 0; r < 4; ++r) h[r] = (_Float16)v[r];
            ((f16x4*)wdst)[i] = h;
        }
    }
}

// ---- M2 partials: K-split Gram; each wave computes a 32x32 region over a 512-px chunk ----
__global__ __launch_bounds__(256) void m2_kernel(const _Float16* xh, float* Pm2) {
    int xi = blockIdx.y, b = blockIdx.z;
    int xb = xi * 2 + b;
    const _Float16* X = xh + (size_t)xb * CIN * HW;
    int bx = blockIdx.x;              // 0..127 = chunk*16 + blk
    int chunk = bx >> 4, blk = bx & 15;
    int t = threadIdx.x; int wv = t >> 6; int L = t & 63; int m = L & 15; int quad = L >> 4;
    int region = blk * 4 + wv;        // 0..63
    int r1 = (region >> 3) * 32, r2 = (region & 7) * 32;
    int p0 = chunk * 512 + quad * 8;
    const f16x8* A0 = (const f16x8*)(X + (size_t)(r1 + m) * HW + p0);
    const f16x8* A1 = (const f16x8*)(X + (size_t)(r1 + 16 + m) * HW + p0);
    const f16x8* B0 = (const f16x8*)(X + (size_t)(r2 + m) * HW + p0);
    const f16x8* B1 = (const f16x8*)(X + (size_t)(r2 + 16 + m) * HW + p0);
    f32x4 zero = {0, 0, 0, 0};
    f32x4 acc00 = zero, acc01 = zero, acc10 = zero, acc11 = zero;
#pragma unroll 4
    for (int it = 0; it < 16; ++it) {
        f16x8 a0 = A0[it * 4], a1 = A1[it * 4];
        f16x8 b0 = B0[it * 4], b1 = B1[it * 4];
        acc00 = __builtin_amdgcn_mfma_f32_16x16x32_f16(a0, b0, acc00, 0, 0, 0);
        acc01 = __builtin_amdgcn_mfma_f32_16x16x32_f16(a0, b1, acc01, 0, 0, 0);
        acc10 = __builtin_amdgcn_mfma_f32_16x16x32_f16(a1, b0, acc10, 0, 0, 0);
        acc11 = __builtin_amdgcn_mfma_f32_16x16x32_f16(a1, b1, acc11, 0, 0, 0);
    }
    float* dst = Pm2 + ((size_t)chunk * 6 + xb) * 65536;
#pragma unroll
    for (int r = 0; r < 4; ++r) {
        int row0 = (r1 + quad * 4 + r) * 256, row1 = (r1 + 16 + quad * 4 + r) * 256;
        dst[row0 + r2 + m] = acc00[r];
        dst[row0 + r2 + 16 + m] = acc01[r];
        dst[row1 + r2 + m] = acc10[r];
        dst[row1 + r2 + 16 + m] = acc11[r];
    }
}

// ---- combine M2 partials over 8 chunks ----
__global__ __launch_bounds__(256) void m2combine_kernel(const float* Pm2, float* M2) {
    size_t e = (size_t)blockIdx.x * 256 + threadIdx.x;   // 0 .. 6*65536-1
    float s = 0.f;
#pragma unroll
    for (int c = 0; c < 8; ++c) s += Pm2[(size_t)c * 6 * 65536 + e];
    M2[e] = s * (1.f / HW);
}

// ---------------- per-(x,b,o) affine params from stats (q pre-scaled by log2e) ----------------
__global__ __launch_bounds__(256) void stats_kernel(const float* M2, const float* mean,
        const float* W1, const float* W2, const float* W3,
        const float* g1, const float* g2, const float* g3,
        const float* b1, const float* b2, const float* b3, float2* afine) {
    int o = blockIdx.x; int xi = blockIdx.y; int b = blockIdx.z;
    int widx = o >> 5; int oc = o & 31;
    const float* Wp = (widx == 0 ? W1 : widx == 1 ? W2 : W3) + oc * CIN;
    const float* gp = (widx == 0 ? g1 : widx == 1 ? g2 : g3);
    const float* bp = (widx == 0 ? b1 : widx == 1 ? b2 : b3);
    int t = threadIdx.x;
    __shared__ float sW[256];
    __shared__ float red[256];
    sW[t] = Wp[t];
    __syncthreads();
    const float* m2row = M2 + ((size_t)(xi * 2 + b) * CIN + t) * CIN;
    float tv = 0.f;
    const f32x4* r4 = (const f32x4*)m2row;
#pragma unroll 4
    for (int k = 0; k < 64; ++k) {
        f32x4 mv = r4[k];
        const f32x4 wv = *(const f32x4*)&sW[k * 4];
        tv += mv[0] * wv[0] + mv[1] * wv[1] + mv[2] * wv[2] + mv[3] * wv[3];
    }
    red[t] = tv * sW[t]; __syncthreads();
    for (int k = 128; k; k >>= 1) { if (t < k) red[t] += red[t + k]; __syncthreads(); }
    float E2 = red[0]; __syncthreads();
    red[t] = sW[t] * mean[(xi * 2 + b) * CIN + t]; __syncthreads();
    for (int k = 128; k; k >>= 1) { if (t < k) red[t] += red[t + k]; __syncthreads(); }
    if (t == 0) {
        float mu = red[0];
        float var = E2 - mu * mu;
        float rsig = rsqrtf(var + 1e-5f);
        float scale = gp[oc] * rsig;
        float bias = bp[oc] - mu * scale;
        if (widx == 0) { scale *= L2E; bias *= L2E; }   // q carries log2e so S' = S*log2e
        afine[(xi * 2 + b) * 96 + o] = make_float2(scale, bias);
    }
}

// ---- conv + norm + relu: writes qT/kT (fp16, pixel-major) and v (fp32 out) ----
__global__ __launch_bounds__(256) void conv_kernel(const _Float16* xh, const _Float16* wh,
        const float2* afine, _Float16* qT, _Float16* kT, float* out) {
    int xi = blockIdx.y, b = blockIdx.z;
    const u16* xb = (const u16*)(xh + (size_t)(xi * 2 + b) * CIN * HW);
    int p0 = blockIdx.x * 64;
    __shared__ u16 lds[32 * 65 * 8];
    int t = threadIdx.x;
    {   // stage x[256][64] into LDS, transposed to 8-channel cells [cblk][f(p)][8c]
        int pc = t & 7, cg = t >> 3;
        u16x8 a[8];
#pragma unroll
        for (int r = 0; r < 8; ++r)
            a[r] = *(const u16x8*)(xb + (size_t)(cg * 8 + r) * HW + p0 + pc * 8);
#pragma unroll
        for (int i = 0; i < 8; ++i) {
            u16x8 d;
#pragma unroll
            for (int r = 0; r < 8; ++r) d[r] = a[r][i];
            int p = pc * 8 + i; int fp = p ^ (p >> 3);
            *(u16x8*)&lds[(cg * 65 + fp) * 8] = d;
        }
    }
    __syncthreads();
    int wv = t >> 6, L = t & 63, m = L & 15, quad = L >> 4;
    int pw0 = wv * 16;
    f16x8 af[8];
    {
        int p = pw0 + m; int fp = p ^ (p >> 3);
#pragma unroll
        for (int k = 0; k < 8; ++k)
            af[k] = *(const f16x8*)&lds[((k * 4 + quad) * 65 + fp) * 8];
    }
    int xb2 = xi * 2 + b;
    for (int ot = 0; ot < 6; ++ot) {
        int o0 = ot * 16; int widx = ot >> 1;
        int o_col = o0 + m;                         // global output channel 0..95
        f32x4 acc = {0, 0, 0, 0};
#pragma unroll
        for (int k = 0; k < 8; ++k) {
            f16x8 bfr = *(const f16x8*)(wh + (size_t)o_col * CIN + k * 32 + quad * 8);
            acc = __builtin_amdgcn_mfma_f32_16x16x32_f16(af[k], bfr, acc, 0, 0, 0);
        }
        float2 afv = afine[xb2 * 96 + o_col];
        f32x4 vals;
#pragma unroll
        for (int r = 0; r < 4; ++r) {
            float v = acc[r] * afv.x + afv.y;
            vals[r] = v > 0.f ? v : 0.f;
        }
        int prow = p0 + pw0 + quad * 4;
        if (widx < 2) {
            _Float16* dst = (widx == 0 ? qT : kT) + (size_t)xb2 * HW32;
            int cc = (o0 & 31) + m;
#pragma unroll
            for (int r = 0; r < 4; ++r)
                dst[(size_t)(prow + r) * 32 + cc] = (_Float16)vals[r];
        } else {
            float* dst = out + (size_t)(5 + xi) * 262144 + (size_t)b * 131072 + (size_t)(o_col - 64) * HW + prow;
            *(f32x4*)dst = vals;    // fp32 output, 4 consecutive pixels
        }
    }
}

// ---- Z-sweep: 4 q-tiles/wave, 16 j-chunks; partial (m,l) per (mat,b,chunk,row) ----
__global__ __launch_bounds__(256) void zsweep_kernel(const _Float16* qT, const _Float16* kT,
        float2* Pz) {
    const int qxA[5] = {0, 1, 1, 2, 0};   // mats: A12 A21 A23 A32 A13
    const int kxA[5] = {1, 0, 2, 1, 2};
    int mat = blockIdx.y, b = blockIdx.z;
    const _Float16* qb = qT + (size_t)(qxA[mat] * 2 + b) * HW32;
    const _Float16* kb = kT + (size_t)(kxA[mat] * 2 + b) * HW32;
    int bx = blockIdx.x;                 // 16 qblk x 16 jc
    int jc = bx & 15, qblk = bx >> 4;
    int t = threadIdx.x; int wv = t >> 6; int L = t & 63; int m = L & 15; int quad = L >> 4;
    int i0 = qblk * 256 + wv * 64;       // wave covers 64 q rows (4 tiles)
    f16x8 a[4];
#pragma unroll
    for (int tt = 0; tt < 4; ++tt)
        a[tt] = *(const f16x8*)(qb + (size_t)(i0 + tt * 16 + m) * 32 + quad * 8);
    const f16x8* kp = (const f16x8*)(kb + m * 32 + quad * 8) + (size_t)jc * (16 * 64);
    f32x4 zero = {0.f, 0.f, 0.f, 0.f};
    f32x4 mx[4] = {zero, zero, zero, zero};
#pragma unroll 4
    for (int j = 0; j < 16; ++j) {
        f16x8 bf = kp[j * 64];
#pragma unroll
        for (int tt = 0; tt < 4; ++tt) {
            f32x4 d = __builtin_amdgcn_mfma_f32_16x16x32_f16(a[tt], bf, zero, 0, 0, 0);
            mx[tt][0] = fmaxf(mx[tt][0], d[0]); mx[tt][1] = fmaxf(mx[tt][1], d[1]);
            mx[tt][2] = fmaxf(mx[tt][2], d[2]); mx[tt][3] = fmaxf(mx[tt][3], d[3]);
        }
    }
#pragma unroll
    for (int tt = 0; tt < 4; ++tt)
#pragma unroll
        for (int msk = 1; msk <= 8; msk <<= 1) {
            mx[tt][0] = fmaxf(mx[tt][0], __shfl_xor(mx[tt][0], msk));
            mx[tt][1] = fmaxf(mx[tt][1], __shfl_xor(mx[tt][1], msk));
            mx[tt][2] = fmaxf(mx[tt][2], __shfl_xor(mx[tt][2], msk));
            mx[tt][3] = fmaxf(mx[tt][3], __shfl_xor(mx[tt][3], msk));
        }
    f32x4 neg[4];
#pragma unroll
    for (int tt = 0; tt < 4; ++tt) neg[tt] = -mx[tt];
    f32x4 z[4] = {zero, zero, zero, zero};
#pragma unroll 4
    for (int j = 0; j < 16; ++j) {
        f16x8 bf = kp[j * 64];
#pragma unroll
        for (int tt = 0; tt < 4; ++tt) {
            f32x4 d = __builtin_amdgcn_mfma_f32_16x16x32_f16(a[tt], bf, neg[tt], 0, 0, 0);
            z[tt][0] += fexp2(d[0]); z[tt][1] += fexp2(d[1]);
            z[tt][2] += fexp2(d[2]); z[tt][3] += fexp2(d[3]);
        }
    }
#pragma unroll
    for (int tt = 0; tt < 4; ++tt)
#pragma unroll
        for (int msk = 1; msk <= 8; msk <<= 1) {
            z[tt][0] += __shfl_xor(z[tt][0], msk); z[tt][1] += __shfl_xor(z[tt][1], msk);
            z[tt][2] += __shfl_xor(z[tt][2], msk); z[tt][3] += __shfl_xor(z[tt][3], msk);
        }
    if (m == 0) {
        int mb = mat * 2 + b;
#pragma unroll
        for (int tt = 0; tt < 4; ++tt) {
            int row = i0 + tt * 16 + quad * 4;
#pragma unroll
            for (int r = 0; r < 4; ++r)
                Pz[((size_t)mb * 16 + jc) * HW + row + r] = make_float2(mx[tt][r], z[tt][r]);
        }
    }
}

// ---- combine zsweep partials: M = max m_c, Z = sum l_c * 2^(m_c - M) ----
__global__ __launch_bounds__(256) void zcombine_kernel(const float2* Pz, float* R, float* Mv, float2* Wa) {
    int mb = blockIdx.y;                 // 0..9 = mat*2+b
    int r = blockIdx.x * 256 + threadIdx.x;
    float2 p[16];
    float M = 0.f;
#pragma unroll
    for (int c = 0; c < 16; ++c) {
        p[c] = Pz[((size_t)mb * 16 + c) * HW + r];
        M = fmaxf(M, p[c].x);
    }
    float Z = 0.f;
#pragma unroll
    for (int c = 0; c < 16; ++c) Z += p[c].y * fexp2(p[c].x - M);
    float rz = 1.0f / Z;
    size_t idx = (size_t)mb * HW + r;
    R[idx] = rz; Mv[idx] = M;
    if (mb < 2 || mb >= 8) Wa[idx] = make_float2(rz, 0.f);   // weights for A12 / A13 sweeps
}

// ---- pass2, i-chunked, 4 j-tiles/wave: partial (s1,s2)[ic][b][j] ----
struct PCfg {
    const _Float16* qb; const _Float16* kb;   // bases covering 2 batches
    const float* Mv;                          // [2][HW] row maxes
    const float2* wt;                         // [2][HW] weights per i
    float2* Pp;                               // [(ic*2+b)*HW + j]
    int nit;                                  // i-iters per chunk (chunk = nit*16 rows)
};

__global__ __launch_bounds__(256) void pass2p_kernel(PCfg c0, PCfg c1) {
    PCfg c = (blockIdx.y == 0) ? c0 : c1;
    int b = blockIdx.z;
    int bx = blockIdx.x; int jb = bx & 15; int ic = bx >> 4;
    const _Float16* qb = c.qb + (size_t)b * HW32;
    const _Float16* kb = c.kb + (size_t)b * HW32;
    const float2* wt = c.wt + (size_t)b * HW;
    const float* Mb = c.Mv + (size_t)b * HW;
    int t = threadIdx.x; int wv = t >> 6; int L = t & 63; int m = L & 15; int quad = L >> 4;
    int j0 = jb * 256 + wv * 64;         // wave covers 64 j columns (4 tiles)
    f16x8 bf[4];
#pragma unroll
    for (int tt = 0; tt < 4; ++tt)
        bf[tt] = *(const f16x8*)(kb + (size_t)(j0 + tt * 16 + m) * 32 + quad * 8);
    float a1[4] = {0, 0, 0, 0}, a2[4] = {0, 0, 0, 0};
    int ibase = ic * (c.nit * 16);
#pragma unroll 4
    for (int it = 0; it < c.nit; ++it) {
        int i0 = ibase + it * 16;
        f16x8 av = *(const f16x8*)(qb + (size_t)(i0 + m) * 32 + quad * 8);
        f32x4 Mr = *(const f32x4*)(Mb + i0 + quad * 4);
        f32x4 negM = -Mr;
        const float2* wr = wt + i0 + quad * 4;
        float2 w0 = wr[0], w1 = wr[1], w2 = wr[2], w3 = wr[3];
#pragma unroll
        for (int tt = 0; tt < 4; ++tt) {
            f32x4 d = __builtin_amdgcn_mfma_f32_16x16x32_f16(av, bf[tt], negM, 0, 0, 0);
            float e0 = fexp2(d[0]), e1 = fexp2(d[1]), e2 = fexp2(d[2]), e3 = fexp2(d[3]);
            a1[tt] += e0 * w0.x + e1 * w1.x + e2 * w2.x + e3 * w3.x;
            a2[tt] += e0 * w0.y + e1 * w1.y + e2 * w2.y + e3 * w3.y;
        }
    }
#pragma unroll
    for (int tt = 0; tt < 4; ++tt) {
        a1[tt] += __shfl_xor(a1[tt], 16); a1[tt] += __shfl_xor(a1[tt], 32);
        a2[tt] += __shfl_xor(a2[tt], 16); a2[tt] += __shfl_xor(a2[tt], 32);
    }
    if (quad == 0) {
        float2* dst = c.Pp + ((size_t)ic * 2 + b) * HW;
#pragma unroll
        for (int tt = 0; tt < 4; ++tt)
            dst[j0 + tt * 16 + m] = make_float2(a1[tt], a2[tt]);
    }
}

// ---- prepA: combine A12/A13 partials -> c12, c13(p3b); build A23 weights ----
__global__ __launch_bounds__(256) void prepA_kernel(const float2* PpA, const float* R,
        float* c12, float* c13, float2* Wa2) {
    int b = blockIdx.y; int j = blockIdx.x * 256 + threadIdx.x;
    float s12 = 0.f, s13 = 0.f;
    for (int ic = 0; ic < 16; ++ic) {
        s12 += PpA[((size_t)ic * 2 + b) * HW + j].x;
        s13 += PpA[((size_t)(16 + ic) * 2 + b) * HW + j].x;
    }
    c12[(size_t)b * HW + j] = s12; c13[(size_t)b * HW + j] = s13;
    float rn = R[((size_t)(2 * 2 + b)) * HW + j];     // 1/Z for A23
    Wa2[(size_t)b * HW + j] = make_float2(rn, s12 * rn);
}

// ---- prep: combine IC partials -> o1,o2; build next weights ----
__global__ __launch_bounds__(256) void prep_kernel(const float2* Pp, const float* Rn,
        const float* aux, float* o1, float* o2, float2* Wn, int IC, int mode) {
    int b = blockIdx.y; int j = blockIdx.x * 256 + threadIdx.x;
    float s1 = 0.f, s2 = 0.f;
    for (int ic = 0; ic < IC; ++ic) {
        float2 p = Pp[((size_t)ic * 2 + b) * HW + j];
        s1 += p.x; s2 += p.y;
    }
    if (o1) o1[(size_t)b * HW + j] = s1;
    if (o2) o2[(size_t)b * HW + j] = s2;
    if (Wn) {
        float rn = Rn[(size_t)b * HW + j];
        float2 w = (mode == 0) ? make_float2(s1 * rn, s2 * rn)
                               : make_float2(s2 * rn, aux[(size_t)b * HW + j] * rn);
        Wn[(size_t)b * HW + j] = w;
    }
}

// ---- broadcast 5 [b,hw] vectors to fp32 [b,32,hw] outputs ----
__global__ __launch_bounds__(256) void bcast_kernel(const float* vecs, float* out) {
    int bx = blockIdx.x;              // 0..319
    int s = bx >> 6; int rem = bx & 63; int b = rem >> 5; int c = rem & 31;
    const float* src = vecs + ((size_t)s * 2 + b) * HW;   // slots 0..4 in output order
    float* dst = out + ((size_t)(s * 2 + b) * 32 + c) * HW;
    int t = threadIdx.x;
#pragma unroll
    for (int k = 0; k < 4; ++k)
        ((f32x4*)dst)[k * 256 + t] = ((const f32x4*)src)[k * 256 + t];
}

extern "C" void kernel_launch(void* const* d_in, const int* in_sizes, int n_in,
                              void* d_out, int out_size, void* d_ws, size_t ws_size,
                              hipStream_t stream) {
    (void)in_sizes; (void)n_in; (void)out_size; (void)ws_size;
    const float* x1 = (const float*)d_in[0];
    const float* x2 = (const float*)d_in[1];
    const float* x3 = (const float*)d_in[2];
    const float* W1 = (const float*)d_in[3];
    const float* g1 = (const float*)d_in[4];
    const float* b1 = (const float*)d_in[5];
    const float* W2 = (const float*)d_in[6];
    const float* g2 = (const float*)d_in[7];
    const float* b2 = (const float*)d_in[8];
    const float* W3 = (const float*)d_in[9];
    const float* g3 = (const float*)d_in[10];
    const float* b3 = (const float*)d_in[11];
    float* out = (float*)d_out;      // reference outputs are float32

    char* w = (char*)d_ws;
    _Float16* xh    = (_Float16*)(w);                    // 12,582,912
    _Float16* wh    = (_Float16*)(w + 12582912);         //     49,152
    float*    mean  = (float*)(w + 12632064);            //      6,144
    float*    M2    = (float*)(w + 12638208);            //  1,572,864
    float2*   afine = (float2*)(w + 14211072);           //      4,608
    _Float16* qT    = (_Float16*)(w + 14215680);         //  1,572,864
    _Float16* kT    = (_Float16*)(w + 15788544);         //  1,572,864
    float*    R     = (float*)(w + 17361408);            //    163,840
    float*    Mv    = (float*)(w + 17525248);            //    163,840
    float2*   Wa    = (float2*)(w + 17689088);           //    327,680
    float*    vecs  = (float*)(w + 18016768);            //    196,608 (6 slots x 2 x HW)
    float2*   Pz    = (float2*)(w + 18213376);           //  5,242,880
    float2*   PpA   = (float2*)(w + 23456256);           //  2,097,152
    float2*   PpB   = (float2*)(w + 25553408);           //  2,097,152
    float2*   PpC   = (float2*)(w + 27650560);           //  2,097,152
    float2*   PpD   = (float2*)(w + 29747712);           //  2,097,152
    // Pm2 overlays Pz/PpA/PpB/PpC (disjoint lifetime: consumed by m2combine before zsweep runs)
    float*    Pm2   = (float*)(w + 18213376);            // 12,582,912 (8 chunks x 6 x 256x256 f32)

    float* v_p1a = vecs + 0 * 2 * HW;
    float* v_p1b = vecs + 1 * 2 * HW;
    float* v_p2  = vecs + 2 * 2 * HW;
    float* v_p3a = vecs + 3 * 2 * HW;
    float* v_p3b = vecs + 4 * 2 * HW;   // c13
    float* v_c12 = vecs + 5 * 2 * HW;

    hipLaunchKernelGGL(convert_kernel, dim3(1542), dim3(256), 0, stream,
                       x1, x2, x3, W1, W2, W3, xh, wh, mean);
    hipLaunchKernelGGL(m2_kernel, dim3(128, 3, 2), dim3(256), 0, stream, xh, Pm2);
    hipLaunchKernelGGL(m2combine_kernel, dim3(1536), dim3(256), 0, stream, Pm2, M2);
    hipLaunchKernelGGL(stats_kernel, dim3(96, 3, 2), dim3(256), 0, stream,
                       M2, mean, W1, W2, W3, g1, g2, g3, b1, b2, b3, afine);
    hipLaunchKernelGGL(conv_kernel, dim3(64, 3, 2), dim3(256), 0, stream,
                       xh, wh, afine, qT, kT, out);
    hipLaunchKernelGGL(zsweep_kernel, dim3(256, 5, 2), dim3(256), 0, stream, qT, kT, Pz);
    hipLaunchKernelGGL(zcombine_kernel, dim3(16, 10), dim3(256), 0, stream, Pz, R, Mv, Wa);

    // mats: 0:A12(q1,k2) 1:A21(q2,k1) 2:A23(q2,k3) 3:A32(q3,k2) 4:A13(q1,k3)
    // A-pair: A12 and A13 with w = {1/Z, 0}; IC=16 (nit=16)
    PCfg cA0 = { qT + 0 * 2 * HW32, kT + 1 * 2 * HW32, Mv + 0 * 2 * HW, Wa + 0 * 2 * HW, PpA,               16 };
    PCfg cA1 = { qT + 0 * 2 * HW32, kT + 2 * 2 * HW32, Mv + 4 * 2 * HW, Wa + 4 * 2 * HW, PpA + 16 * 2 * HW, 16 };
    hipLaunchKernelGGL(pass2p_kernel, dim3(256, 2, 2), dim3(256), 0, stream, cA0, cA1);
    hipLaunchKernelGGL(prepA_kernel, dim3(16, 2), dim3(256), 0, stream,
                       PpA, R, v_c12, v_p3b, Wa + 2 * 2 * HW);

    // B: A23 sweep (q2,k3), w = {rn23, c12*rn23} -> o1=c23, o2=u1(p3a); IC=32 (nit=8)
    PCfg cB = { qT + 1 * 2 * HW32, kT + 2 * 2 * HW32, Mv + 2 * 2 * HW, Wa + 2 * 2 * HW, PpB, 8 };
    hipLaunchKernelGGL(pass2p_kernel, dim3(512, 1, 2), dim3(256), 0, stream, cB, cB);
    hipLaunchKernelGGL(prep_kernel, dim3(16, 2), dim3(256), 0, stream,
                       PpB, R + 3 * 2 * HW, (const float*)nullptr,
                       (float*)nullptr, v_p3a, Wa + 3 * 2 * HW, 32, 0);

    // C: A32 sweep (q3,k2), w = {c23*rn32, u1*rn32} -> o1=p2, o2=u2; IC=32
    PCfg cC = { qT + 2 * 2 * HW32, kT + 1 * 2 * HW32, Mv + 3 * 2 * HW, Wa + 3 * 2 * HW, PpC, 8 };
    hipLaunchKernelGGL(pass2p_kernel, dim3(512, 1, 2), dim3(256), 0, stream, cC, cC);
    hipLaunchKernelGGL(prep_kernel, dim3(16, 2), dim3(256), 0, stream,
                       PpC, R + 1 * 2 * HW, v_c12,
                       v_p2, (float*)nullptr, Wa + 1 * 2 * HW, 32, 1);

    // D: A21 sweep (q2,k1), w = {u2*rn21, c12*rn21} -> o1=p1a, o2=p1b; IC=32
    PCfg cD = { qT + 1 * 2 * HW32, kT + 0 * 2 * HW32, Mv + 1 * 2 * HW, Wa + 1 * 2 * HW, PpD, 8 };
    hipLaunchKernelGGL(pass2p_kernel, dim3(512, 1, 2), dim3(256), 0, stream, cD, cD);
    hipLaunchKernelGGL(prep_kernel, dim3(16, 2), dim3(256), 0, stream,
                       PpD, (const float*)nullptr, (const float*)nullptr,
                       v_p1a, v_p1b, (float2*)nullptr, 32, 0);

    hipLaunchKernelGGL(bcast_kernel, dim3(320), dim3(256), 0, stream, vecs, out);
}

// Round 8
// 282.151 us; speedup vs baseline: 1.3672x; 1.0394x over previous
//
#include <hip/hip_runtime.h>

typedef unsigned short u16;
typedef u16  u16x8  __attribute__((ext_vector_type(8)));
typedef _Float16 f16x4 __attribute__((ext_vector_type(4)));
typedef _Float16 f16x8 __attribute__((ext_vector_type(8)));
typedef float f32x4 __attribute__((ext_vector_type(4)));

#define HW 4096
#define CIN 256
#define HW32 (HW * 32)
#define L2E 1.4426950408889634f

__device__ __forceinline__ float fexp2(float x) { return __builtin_amdgcn_exp2f(x); }

// ---------------- convert x (fp32->fp16) + channel means; convert W ----------------
__global__ __launch_bounds__(256) void convert_kernel(const float* x1, const float* x2, const float* x3,
        const float* W1, const float* W2, const float* W3,
        _Float16* xh, _Float16* wh, float* mean) {
    int bx = blockIdx.x; int t = threadIdx.x;
    if (bx < 1536) {
        int xi = bx >> 9, b = (bx >> 8) & 1, c = bx & 255;
        const float* src = (xi == 0 ? x1 : xi == 1 ? x2 : x3) + (size_t)(b * CIN + c) * HW;
        _Float16* dst = xh + ((size_t)((xi * 2 + b) * CIN) + c) * HW;
        float s = 0.f;
        for (int i = t; i < 1024; i += 256) {
            f32x4 v = ((const f32x4*)src)[i];
            s += v[0] + v[1] + v[2] + v[3];
            f16x4 h;
#pragma unroll
            for (int r = 0; r < 4; ++r) h[r] = (_Float16)v[r];
            ((f16x4*)dst)[i] = h;
        }
        __shared__ float red[256];
        red[t] = s; __syncthreads();
        for (int k = 128; k; k >>= 1) { if (t < k) red[t] += red[t + k]; __syncthreads(); }
        if (t == 0) mean[(xi * 2 + b) * CIN + c] = red[0] * (1.f / HW);
    } else {
        int j = bx - 1536;                 // 0..5
        int widx = j >> 1, half = j & 1;
        const float* wsrc = (widx == 0 ? W1 : widx == 1 ? W2 : W3) + half * 4096;
        _Float16* wdst = wh + widx * 8192 + half * 4096;
        for (int i = t; i < 1024; i += 256) {
            f32x4 v = ((const f32x4*)wsrc)[i];
            f16x4 h;
#pragma unroll
            for (int r = 0; r < 4; ++r) h[r] = (_Float16)v[r];
            ((f16x4*)wdst)[i] = h;
        }
    }
}

// ---- M2 partials: K-split Gram; each wave computes a 32x32 region over a 512-px chunk ----
__global__ __launch_bounds__(256) void m2_kernel(const _Float16* xh, float* Pm2) {
    int xi = blockIdx.y, b = blockIdx.z;
    int xb = xi * 2 + b;
    const _Float16* X = xh + (size_t)xb * CIN * HW;
    int bx = blockIdx.x;              // 0..127 = chunk*16 + blk
    int chunk = bx >> 4, blk = bx & 15;
    int t = threadIdx.x; int wv = t >> 6; int L = t & 63; int m = L & 15; int quad = L >> 4;
    int region = blk * 4 + wv;        // 0..63
    int r1 = (region >> 3) * 32, r2 = (region & 7) * 32;
    int p0 = chunk * 512 + quad * 8;
    const f16x8* A0 = (const f16x8*)(X + (size_t)(r1 + m) * HW + p0);
    const f16x8* A1 = (const f16x8*)(X + (size_t)(r1 + 16 + m) * HW + p0);
    const f16x8* B0 = (const f16x8*)(X + (size_t)(r2 + m) * HW + p0);
    const f16x8* B1 = (const f16x8*)(X + (size_t)(r2 + 16 + m) * HW + p0);
    f32x4 zero = {0, 0, 0, 0};
    f32x4 acc00 = zero, acc01 = zero, acc10 = zero, acc11 = zero;
#pragma unroll 4
    for (int it = 0; it < 16; ++it) {
        f16x8 a0 = A0[it * 4], a1 = A1[it * 4];
        f16x8 b0 = B0[it * 4], b1 = B1[it * 4];
        acc00 = __builtin_amdgcn_mfma_f32_16x16x32_f16(a0, b0, acc00, 0, 0, 0);
        acc01 = __builtin_amdgcn_mfma_f32_16x16x32_f16(a0, b1, acc01, 0, 0, 0);
        acc10 = __builtin_amdgcn_mfma_f32_16x16x32_f16(a1, b0, acc10, 0, 0, 0);
        acc11 = __builtin_amdgcn_mfma_f32_16x16x32_f16(a1, b1, acc11, 0, 0, 0);
    }
    float* dst = Pm2 + ((size_t)chunk * 6 + xb) * 65536;
#pragma unroll
    for (int r = 0; r < 4; ++r) {
        int row0 = (r1 + quad * 4 + r) * 256, row1 = (r1 + 16 + quad * 4 + r) * 256;
        dst[row0 + r2 + m] = acc00[r];
        dst[row0 + r2 + 16 + m] = acc01[r];
        dst[row1 + r2 + m] = acc10[r];
        dst[row1 + r2 + 16 + m] = acc11[r];
    }
}

// ---- combine M2 partials over 8 chunks ----
__global__ __launch_bounds__(256) void m2combine_kernel(const float* Pm2, float* M2) {
    size_t e = (size_t)blockIdx.x * 256 + threadIdx.x;   // 0 .. 6*65536-1
    float s = 0.f;
#pragma unroll
    for (int c = 0; c < 8; ++c) s += Pm2[(size_t)c * 6 * 65536 + e];
    M2[e] = s * (1.f / HW);
}

// ---------------- per-(x,b,o) affine params from stats (q pre-scaled by log2e) ----------------
__global__ __launch_bounds__(256) void stats_kernel(const float* M2, const float* mean,
        const float* W1, const float* W2, const float* W3,
        const float* g1, const float* g2, const float* g3,
        const float* b1, const float* b2, const float* b3, float2* afine) {
    int o = blockIdx.x; int xi = blockIdx.y; int b = blockIdx.z;
    int widx = o >> 5; int oc = o & 31;
    const float* Wp = (widx == 0 ? W1 : widx == 1 ? W2 : W3) + oc * CIN;
    const float* gp = (widx == 0 ? g1 : widx == 1 ? g2 : g3);
    const float* bp = (widx == 0 ? b1 : widx == 1 ? b2 : b3);
    int t = threadIdx.x;
    __shared__ float sW[256];
    __shared__ float red[256];
    sW[t] = Wp[t];
    __syncthreads();
    const float* m2row = M2 + ((size_t)(xi * 2 + b) * CIN + t) * CIN;
    float tv = 0.f;
    const f32x4* r4 = (const f32x4*)m2row;
#pragma unroll 4
    for (int k = 0; k < 64; ++k) {
        f32x4 mv = r4[k];
        const f32x4 wv = *(const f32x4*)&sW[k * 4];
        tv += mv[0] * wv[0] + mv[1] * wv[1] + mv[2] * wv[2] + mv[3] * wv[3];
    }
    red[t] = tv * sW[t]; __syncthreads();
    for (int k = 128; k; k >>= 1) { if (t < k) red[t] += red[t + k]; __syncthreads(); }
    float E2 = red[0]; __syncthreads();
    red[t] = sW[t] * mean[(xi * 2 + b) * CIN + t]; __syncthreads();
    for (int k = 128; k; k >>= 1) { if (t < k) red[t] += red[t + k]; __syncthreads(); }
    if (t == 0) {
        float mu = red[0];
        float var = E2 - mu * mu;
        float rsig = rsqrtf(var + 1e-5f);
        float scale = gp[oc] * rsig;
        float bias = bp[oc] - mu * scale;
        if (widx == 0) { scale *= L2E; bias *= L2E; }   // q carries log2e so S' = S*log2e
        afine[(xi * 2 + b) * 96 + o] = make_float2(scale, bias);
    }
}

// ---- conv + norm + relu: writes qT/kT (fp16, pixel-major) and v (fp32 out) ----
__global__ __launch_bounds__(256) void conv_kernel(const _Float16* xh, const _Float16* wh,
        const float2* afine, _Float16* qT, _Float16* kT, float* out) {
    int xi = blockIdx.y, b = blockIdx.z;
    const u16* xb = (const u16*)(xh + (size_t)(xi * 2 + b) * CIN * HW);
    int p0 = blockIdx.x * 64;
    __shared__ u16 lds[32 * 65 * 8];
    int t = threadIdx.x;
    {   // stage x[256][64] into LDS, transposed to 8-channel cells [cblk][f(p)][8c]
        int pc = t & 7, cg = t >> 3;
        u16x8 a[8];
#pragma unroll
        for (int r = 0; r < 8; ++r)
            a[r] = *(const u16x8*)(xb + (size_t)(cg * 8 + r) * HW + p0 + pc * 8);
#pragma unroll
        for (int i = 0; i < 8; ++i) {
            u16x8 d;
#pragma unroll
            for (int r = 0; r < 8; ++r) d[r] = a[r][i];
            int p = pc * 8 + i; int fp = p ^ (p >> 3);
            *(u16x8*)&lds[(cg * 65 + fp) * 8] = d;
        }
    }
    __syncthreads();
    int wv = t >> 6, L = t & 63, m = L & 15, quad = L >> 4;
    int pw0 = wv * 16;
    f16x8 af[8];
    {
        int p = pw0 + m; int fp = p ^ (p >> 3);
#pragma unroll
        for (int k = 0; k < 8; ++k)
            af[k] = *(const f16x8*)&lds[((k * 4 + quad) * 65 + fp) * 8];
    }
    int xb2 = xi * 2 + b;
    for (int ot = 0; ot < 6; ++ot) {
        int o0 = ot * 16; int widx = ot >> 1;
        int o_col = o0 + m;                         // global output channel 0..95
        f32x4 acc = {0, 0, 0, 0};
#pragma unroll
        for (int k = 0; k < 8; ++k) {
            f16x8 bfr = *(const f16x8*)(wh + (size_t)o_col * CIN + k * 32 + quad * 8);
            acc = __builtin_amdgcn_mfma_f32_16x16x32_f16(af[k], bfr, acc, 0, 0, 0);
        }
        float2 afv = afine[xb2 * 96 + o_col];
        f32x4 vals;
#pragma unroll
        for (int r = 0; r < 4; ++r) {
            float v = acc[r] * afv.x + afv.y;
            vals[r] = v > 0.f ? v : 0.f;
        }
        int prow = p0 + pw0 + quad * 4;
        if (widx < 2) {
            _Float16* dst = (widx == 0 ? qT : kT) + (size_t)xb2 * HW32;
            int cc = (o0 & 31) + m;
#pragma unroll
            for (int r = 0; r < 4; ++r)
                dst[(size_t)(prow + r) * 32 + cc] = (_Float16)vals[r];
        } else {
            float* dst = out + (size_t)(5 + xi) * 262144 + (size_t)b * 131072 + (size_t)(o_col - 64) * HW + prow;
            *(f32x4*)dst = vals;    // fp32 output, 4 consecutive pixels
        }
    }
}

// ---- max row-norms of q/k tensors -> Cauchy-Schwarz softmax shift bounds ----
__global__ __launch_bounds__(256) void maxnorm_kernel(const _Float16* qT, const _Float16* kT,
                                                      float* maxq, float* maxk) {
    int id = blockIdx.x;              // 0..11
    int which = id >> 1; int b = id & 1;
    const _Float16* base = (which < 3 ? qT + (size_t)(which * 2 + b) * HW32
                                      : kT + (size_t)((which - 3) * 2 + b) * HW32);
    int t = threadIdx.x;
    float mx = 0.f;
    for (int i = t; i < HW; i += 256) {
        const f16x8* r = (const f16x8*)(base + (size_t)i * 32);
        float s = 0.f;
#pragma unroll
        for (int k = 0; k < 4; ++k) {
            f16x8 v = r[k];
#pragma unroll
            for (int j = 0; j < 8; ++j) { float f = (float)v[j]; s += f * f; }
        }
        mx = fmaxf(mx, s);
    }
    __shared__ float red[256];
    red[t] = mx; __syncthreads();
    for (int k = 128; k; k >>= 1) { if (t < k) red[t] = fmaxf(red[t], red[t + k]); __syncthreads(); }
    if (t == 0) {
        float v = sqrtf(red[0]);
        if (which < 3) maxq[which * 2 + b] = v; else maxk[(which - 3) * 2 + b] = v;
    }
}

// ---- Z-sweep (single pass, constant shift): per-chunk partial Z sums ----
__global__ __launch_bounds__(256) void zsweep_kernel(const _Float16* qT, const _Float16* kT,
        const float* maxq, const float* maxk, float* Pz) {
    const int qxA[5] = {0, 1, 1, 2, 0};   // mats: A12 A21 A23 A32 A13
    const int kxA[5] = {1, 0, 2, 1, 2};
    int mat = blockIdx.y, b = blockIdx.z;
    const _Float16* qb = qT + (size_t)(qxA[mat] * 2 + b) * HW32;
    const _Float16* kb = kT + (size_t)(kxA[mat] * 2 + b) * HW32;
    float Cg = maxq[qxA[mat] * 2 + b] * maxk[kxA[mat] * 2 + b];   // already log2-domain (q scaled by L2E)
    int bx = blockIdx.x;                 // 16 qblk x 16 jc
    int jc = bx & 15, qblk = bx >> 4;
    int t = threadIdx.x; int wv = t >> 6; int L = t & 63; int m = L & 15; int quad = L >> 4;
    int i0 = qblk * 256 + wv * 64;       // wave covers 64 q rows (4 tiles)
    f16x8 a[4];
#pragma unroll
    for (int tt = 0; tt < 4; ++tt)
        a[tt] = *(const f16x8*)(qb + (size_t)(i0 + tt * 16 + m) * 32 + quad * 8);
    const f16x8* kp = (const f16x8*)(kb + m * 32 + quad * 8) + (size_t)jc * (16 * 64);
    f32x4 negC = {-Cg, -Cg, -Cg, -Cg};
    f32x4 zero = {0.f, 0.f, 0.f, 0.f};
    f32x4 z[4] = {zero, zero, zero, zero};
#pragma unroll 4
    for (int j = 0; j < 16; ++j) {
        f16x8 bf = kp[j * 64];
#pragma unroll
        for (int tt = 0; tt < 4; ++tt) {
            f32x4 d = __builtin_amdgcn_mfma_f32_16x16x32_f16(a[tt], bf, negC, 0, 0, 0);
            z[tt][0] += fexp2(d[0]); z[tt][1] += fexp2(d[1]);
            z[tt][2] += fexp2(d[2]); z[tt][3] += fexp2(d[3]);
        }
    }
#pragma unroll
    for (int tt = 0; tt < 4; ++tt)
#pragma unroll
        for (int msk = 1; msk <= 8; msk <<= 1) {
            z[tt][0] += __shfl_xor(z[tt][0], msk); z[tt][1] += __shfl_xor(z[tt][1], msk);
            z[tt][2] += __shfl_xor(z[tt][2], msk); z[tt][3] += __shfl_xor(z[tt][3], msk);
        }
    if (m == 0) {
        int mb = mat * 2 + b;
#pragma unroll
        for (int tt = 0; tt < 4; ++tt) {
            int row = i0 + tt * 16 + quad * 4;
#pragma unroll
            for (int r = 0; r < 4; ++r)
                Pz[((size_t)mb * 16 + jc) * HW + row + r] = z[tt][r];
        }
    }
}

// ---- combine zsweep partials (shared shift): Z = sum, R = 1/Z ----
__global__ __launch_bounds__(256) void zcombine_kernel(const float* Pz, float* R, float2* Wa) {
    int mb = blockIdx.y;                 // 0..9 = mat*2+b
    int r = blockIdx.x * 256 + threadIdx.x;
    float Z = 0.f;
#pragma unroll
    for (int c = 0; c < 16; ++c) Z += Pz[((size_t)mb * 16 + c) * HW + r];
    float rz = 1.0f / Z;
    size_t idx = (size_t)mb * HW + r;
    R[idx] = rz;
    if (mb < 2 || mb >= 8) Wa[idx] = make_float2(rz, 0.f);   // weights for A12 / A13 sweeps
}

// ---- pass2, i-chunked, 4 j-tiles/wave, constant shift: partial (s1,s2)[ic][b][j] ----
struct PCfg {
    const _Float16* qb; const _Float16* kb;   // bases covering 2 batches
    const float* mq; const float* mk;         // per-batch shift factors
    const float2* wt;                         // [2][HW] weights per i
    float2* Pp;                               // [(ic*2+b)*HW + j]
    int nit;                                  // i-iters per chunk (chunk = nit*16 rows)
};

__global__ __launch_bounds__(256) void pass2p_kernel(PCfg c0, PCfg c1) {
    PCfg c = (blockIdx.y == 0) ? c0 : c1;
    int b = blockIdx.z;
    int bx = blockIdx.x; int jb = bx & 15; int ic = bx >> 4;
    const _Float16* qb = c.qb + (size_t)b * HW32;
    const _Float16* kb = c.kb + (size_t)b * HW32;
    const float2* wt = c.wt + (size_t)b * HW;
    float Cg = c.mq[b] * c.mk[b];
    int t = threadIdx.x; int wv = t >> 6; int L = t & 63; int m = L & 15; int quad = L >> 4;
    int j0 = jb * 256 + wv * 64;         // wave covers 64 j columns (4 tiles)
    f16x8 bf[4];
#pragma unroll
    for (int tt = 0; tt < 4; ++tt)
        bf[tt] = *(const f16x8*)(kb + (size_t)(j0 + tt * 16 + m) * 32 + quad * 8);
    f32x4 negC = {-Cg, -Cg, -Cg, -Cg};
    float a1[4] = {0, 0, 0, 0}, a2[4] = {0, 0, 0, 0};
    int ibase = ic * (c.nit * 16);
#pragma unroll 4
    for (int it = 0; it < c.nit; ++it) {
        int i0 = ibase + it * 16;
        f16x8 av = *(const f16x8*)(qb + (size_t)(i0 + m) * 32 + quad * 8);
        const float2* wr = wt + i0 + quad * 4;
        float2 w0 = wr[0], w1 = wr[1], w2 = wr[2], w3 = wr[3];
#pragma unroll
        for (int tt = 0; tt < 4; ++tt) {
            f32x4 d = __builtin_amdgcn_mfma_f32_16x16x32_f16(av, bf[tt], negC, 0, 0, 0);
            float e0 = fexp2(d[0]), e1 = fexp2(d[1]), e2 = fexp2(d[2]), e3 = fexp2(d[3]);
            a1[tt] += e0 * w0.x + e1 * w1.x + e2 * w2.x + e3 * w3.x;
            a2[tt] += e0 * w0.y + e1 * w1.y + e2 * w2.y + e3 * w3.y;
        }
    }
#pragma unroll
    for (int tt = 0; tt < 4; ++tt) {
        a1[tt] += __shfl_xor(a1[tt], 16); a1[tt] += __shfl_xor(a1[tt], 32);
        a2[tt] += __shfl_xor(a2[tt], 16); a2[tt] += __shfl_xor(a2[tt], 32);
    }
    if (quad == 0) {
        float2* dst = c.Pp + ((size_t)ic * 2 + b) * HW;
#pragma unroll
        for (int tt = 0; tt < 4; ++tt)
            dst[j0 + tt * 16 + m] = make_float2(a1[tt], a2[tt]);
    }
}

// ---- prepA: combine A12/A13 partials -> c12, c13(p3b); build A23 weights ----
__global__ __launch_bounds__(256) void prepA_kernel(const float2* PpA, const float* R,
        float* c12, float* c13, float2* Wa2) {
    int b = blockIdx.y; int j = blockIdx.x * 256 + threadIdx.x;
    float s12 = 0.f, s13 = 0.f;
    for (int ic = 0; ic < 16; ++ic) {
        s12 += PpA[((size_t)ic * 2 + b) * HW + j].x;
        s13 += PpA[((size_t)(16 + ic) * 2 + b) * HW + j].x;
    }
    c12[(size_t)b * HW + j] = s12; c13[(size_t)b * HW + j] = s13;
    float rn = R[((size_t)(2 * 2 + b)) * HW + j];     // 1/Z for A23
    Wa2[(size_t)b * HW + j] = make_float2(rn, s12 * rn);
}

// ---- prep: combine IC partials -> o1,o2; build next weights ----
__global__ __launch_bounds__(256) void prep_kernel(const float2* Pp, const float* Rn,
        const float* aux, float* o1, float* o2, float2* Wn, int IC, int mode) {
    int b = blockIdx.y; int j = blockIdx.x * 256 + threadIdx.x;
    float s1 = 0.f, s2 = 0.f;
    for (int ic = 0; ic < IC; ++ic) {
        float2 p = Pp[((size_t)ic * 2 + b) * HW + j];
        s1 += p.x; s2 += p.y;
    }
    if (o1) o1[(size_t)b * HW + j] = s1;
    if (o2) o2[(size_t)b * HW + j] = s2;
    if (Wn) {
        float rn = Rn[(size_t)b * HW + j];
        float2 w = (mode == 0) ? make_float2(s1 * rn, s2 * rn)
                               : make_float2(s2 * rn, aux[(size_t)b * HW + j] * rn);
        Wn[(size_t)b * HW + j] = w;
    }
}

// ---- broadcast 5 [b,hw] vectors to fp32 [b,32,hw] outputs ----
__global__ __launch_bounds__(256) void bcast_kernel(const float* vecs, float* out) {
    int bx = blockIdx.x;              // 0..319
    int s = bx >> 6; int rem = bx & 63; int b = rem >> 5; int c = rem & 31;
    const float* src = vecs + ((size_t)s * 2 + b) * HW;   // slots 0..4 in output order
    float* dst = out + ((size_t)(s * 2 + b) * 32 + c) * HW;
    int t = threadIdx.x;
#pragma unroll
    for (int k = 0; k < 4; ++k)
        ((f32x4*)dst)[k * 256 + t] = ((const f32x4*)src)[k * 256 + t];
}

extern "C" void kernel_launch(void* const* d_in, const int* in_sizes, int n_in,
                              void* d_out, int out_size, void* d_ws, size_t ws_size,
                              hipStream_t stream) {
    (void)in_sizes; (void)n_in; (void)out_size; (void)ws_size;
    const float* x1 = (const float*)d_in[0];
    const float* x2 = (const float*)d_in[1];
    const float* x3 = (const float*)d_in[2];
    const float* W1 = (const float*)d_in[3];
    const float* g1 = (const float*)d_in[4];
    const float* b1 = (const float*)d_in[5];
    const float* W2 = (const float*)d_in[6];
    const float* g2 = (const float*)d_in[7];
    const float* b2 = (const float*)d_in[8];
    const float* W3 = (const float*)d_in[9];
    const float* g3 = (const float*)d_in[10];
    const float* b3 = (const float*)d_in[11];
    float* out = (float*)d_out;      // reference outputs are float32

    char* w = (char*)d_ws;
    _Float16* xh    = (_Float16*)(w);                    // 12,582,912
    _Float16* wh    = (_Float16*)(w + 12582912);         //     49,152
    float*    mean  = (float*)(w + 12632064);            //      6,144
    float*    M2    = (float*)(w + 12638208);            //  1,572,864
    float2*   afine = (float2*)(w + 14211072);           //      4,608
    _Float16* qT    = (_Float16*)(w + 14215680);         //  1,572,864
    _Float16* kT    = (_Float16*)(w + 15788544);         //  1,572,864
    float*    R     = (float*)(w + 17361408);            //    163,840
    float*    maxq  = (float*)(w + 17525248);            //         64
    float*    maxk  = (float*)(w + 17525312);            //         64
    float2*   Wa    = (float2*)(w + 17689088);           //    327,680
    float*    vecs  = (float*)(w + 18016768);            //    196,608 (6 slots x 2 x HW)
    float*    Pz    = (float*)(w + 18213376);            //  2,621,440
    float2*   PpA   = (float2*)(w + 23456256);           //  2,097,152
    float2*   PpB   = (float2*)(w + 25553408);           //  2,097,152
    float2*   PpC   = (float2*)(w + 27650560);           //  2,097,152
    float2*   PpD   = (float2*)(w + 29747712);           //  2,097,152
    // Pm2 overlays Pz/PpA/PpB/PpC (disjoint lifetime: consumed by m2combine before zsweep runs)
    float*    Pm2   = (float*)(w + 18213376);            // 12,582,912 (8 chunks x 6 x 256x256 f32)

    float* v_p1a = vecs + 0 * 2 * HW;
    float* v_p1b = vecs + 1 * 2 * HW;
    float* v_p2  = vecs + 2 * 2 * HW;
    float* v_p3a = vecs + 3 * 2 * HW;
    float* v_p3b = vecs + 4 * 2 * HW;   // c13
    float* v_c12 = vecs + 5 * 2 * HW;

    hipLaunchKernelGGL(convert_kernel, dim3(1542), dim3(256), 0, stream,
                       x1, x2, x3, W1, W2, W3, xh, wh, mean);
    hipLaunchKernelGGL(m2_kernel, dim3(128, 3, 2), dim3(256), 0, stream, xh, Pm2);
    hipLaunchKernelGGL(m2combine_kernel, dim3(1536), dim3(256), 0, stream, Pm2, M2);
    hipLaunchKernelGGL(stats_kernel, dim3(96, 3, 2), dim3(256), 0, stream,
                       M2, mean, W1, W2, W3, g1, g2, g3, b1, b2, b3, afine);
    hipLaunchKernelGGL(conv_kernel, dim3(64, 3, 2), dim3(256), 0, stream,
                       xh, wh, afine, qT, kT, out);
    hipLaunchKernelGGL(maxnorm_kernel, dim3(12), dim3(256), 0, stream, qT, kT, maxq, maxk);
    hipLaunchKernelGGL(zsweep_kernel, dim3(256, 5, 2), dim3(256), 0, stream, qT, kT, maxq, maxk, Pz);
    hipLaunchKernelGGL(zcombine_kernel, dim3(16, 10), dim3(256), 0, stream, Pz, R, Wa);

    // mats: 0:A12(q1,k2) 1:A21(q2,k1) 2:A23(q2,k3) 3:A32(q3,k2) 4:A13(q1,k3)
    // A-pair: A12 and A13 with w = {1/Z, 0}; IC=16 (nit=16)
    PCfg cA0 = { qT + 0 * 2 * HW32, kT + 1 * 2 * HW32, maxq + 0, maxk + 2, Wa + 0 * 2 * HW, PpA,               16 };
    PCfg cA1 = { qT + 0 * 2 * HW32, kT + 2 * 2 * HW32, maxq + 0, maxk + 4, Wa + 4 * 2 * HW, PpA + 16 * 2 * HW, 16 };
    hipLaunchKernelGGL(pass2p_kernel, dim3(256, 2, 2), dim3(256), 0, stream, cA0, cA1);
    hipLaunchKernelGGL(prepA_kernel, dim3(16, 2), dim3(256), 0, stream,
                       PpA, R, v_c12, v_p3b, Wa + 2 * 2 * HW);

    // B: A23 sweep (q2,k3), w = {rn23, c12*rn23} -> o1=c23, o2=u1(p3a); IC=32 (nit=8)
    PCfg cB = { qT + 1 * 2 * HW32, kT + 2 * 2 * HW32, maxq + 2, maxk + 4, Wa + 2 * 2 * HW, PpB, 8 };
    hipLaunchKernelGGL(pass2p_kernel, dim3(512, 1, 2), dim3(256), 0, stream, cB, cB);
    hipLaunchKernelGGL(prep_kernel, dim3(16, 2), dim3(256), 0, stream,
                       PpB, R + 3 * 2 * HW, (const float*)nullptr,
                       (float*)nullptr, v_p3a, Wa + 3 * 2 * HW, 32, 0);

    // C: A32 sweep (q3,k2), w = {c23*rn32, u1*rn32} -> o1=p2, o2=u2; IC=32
    PCfg cC = { qT + 2 * 2 * HW32, kT + 1 * 2 * HW32, maxq + 4, maxk + 2, Wa + 3 * 2 * HW, PpC, 8 };
    hipLaunchKernelGGL(pass2p_kernel, dim3(512, 1, 2), dim3(256), 0, stream, cC, cC);
    hipLaunchKernelGGL(prep_kernel, dim3(16, 2), dim3(256), 0, stream,
                       PpC, R + 1 * 2 * HW, v_c12,
                       v_p2, (float*)nullptr, Wa + 1 * 2 * HW, 32, 1);

    // D: A21 sweep (q2,k1), w = {u2*rn21, c12*rn21} -> o1=p1a, o2=p1b; IC=32
    PCfg cD = { qT + 1 * 2 * HW32, kT + 0 * 2 * HW32, maxq + 2, maxk + 0, Wa + 1 * 2 * HW, PpD, 8 };
    hipLaunchKernelGGL(pass2p_kernel, dim3(512, 1, 2), dim3(256), 0, stream, cD, cD);
    hipLaunchKernelGGL(prep_kernel, dim3(16, 2), dim3(256), 0, stream,
                       PpD, (const float*)nullptr, (const float*)nullptr,
                       v_p1a, v_p1b, (float2*)nullptr, 32, 0);

    hipLaunchKernelGGL(bcast_kernel, dim3(320), dim3(256), 0, stream, vecs, out);
}

// Round 9
// 263.238 us; speedup vs baseline: 1.4654x; 1.0718x over previous
//
#include <hip/hip_runtime.h>

typedef unsigned short u16;
typedef u16  u16x8  __attribute__((ext_vector_type(8)));
typedef _Float16 f16x4 __attribute__((ext_vector_type(4)));
typedef _Float16 f16x8 __attribute__((ext_vector_type(8)));
typedef float f32x2 __attribute__((ext_vector_type(2)));
typedef float f32x4 __attribute__((ext_vector_type(4)));

#define HW 4096
#define CIN 256
#define HW32 (HW * 32)
#define L2E 1.4426950408889634f

__device__ __forceinline__ float fexp2(float x) { return __builtin_amdgcn_exp2f(x); }

// ---------------- convert x (fp32->fp16) + channel means; convert W; zero norm slots ----------------
__global__ __launch_bounds__(256) void convert_kernel(const float* x1, const float* x2, const float* x3,
        const float* W1, const float* W2, const float* W3,
        _Float16* xh, _Float16* wh, float* mean, float* maxq, float* maxk) {
    int bx = blockIdx.x; int t = threadIdx.x;
    if (bx < 1536) {
        int xi = bx >> 9, b = (bx >> 8) & 1, c = bx & 255;
        const float* src = (xi == 0 ? x1 : xi == 1 ? x2 : x3) + (size_t)(b * CIN + c) * HW;
        _Float16* dst = xh + ((size_t)((xi * 2 + b) * CIN) + c) * HW;
        float s = 0.f;
        for (int i = t; i < 1024; i += 256) {
            f32x4 v = ((const f32x4*)src)[i];
            s += v[0] + v[1] + v[2] + v[3];
            f16x4 h;
#pragma unroll
            for (int r = 0; r < 4; ++r) h[r] = (_Float16)v[r];
            ((f16x4*)dst)[i] = h;
        }
        __shared__ float red[256];
        red[t] = s; __syncthreads();
        for (int k = 128; k; k >>= 1) { if (t < k) red[t] += red[t + k]; __syncthreads(); }
        if (t == 0) mean[(xi * 2 + b) * CIN + c] = red[0] * (1.f / HW);
    } else {
        int j = bx - 1536;                 // 0..5
        if (j == 0 && t < 12) { if (t < 6) maxq[t] = 0.f; else maxk[t - 6] = 0.f; }
        int widx = j >> 1, half = j & 1;
        const float* wsrc = (widx == 0 ? W1 : widx == 1 ? W2 : W3) + half * 4096;
        _Float16* wdst = wh + widx * 8192 + half * 4096;
        for (int i = t; i < 1024; i += 256) {
            f32x4 v = ((const f32x4*)wsrc)[i];
            f16x4 h;
#pragma unroll
            for (int r = 0; r < 4; ++r) h[r] = (_Float16)v[r];
            ((f16x4*)wdst)[i] = h;
        }
    }
}

// ---- M2 partials: K-split Gram; each wave computes a 32x32 region over a 512-px chunk ----
__global__ __launch_bounds__(256) void m2_kernel(const _Float16* xh, float* Pm2) {
    int xi = blockIdx.y, b = blockIdx.z;
    int xb = xi * 2 + b;
    const _Float16* X = xh + (size_t)xb * CIN * HW;
    int bx = blockIdx.x;              // 0..127 = chunk*16 + blk
    int chunk = bx >> 4, blk = bx & 15;
    int t = threadIdx.x; int wv = t >> 6; int L = t & 63; int m = L & 15; int quad = L >> 4;
    int region = blk * 4 + wv;        // 0..63
    int r1 = (region >> 3) * 32, r2 = (region & 7) * 32;
    int p0 = chunk * 512 + quad * 8;
    const f16x8* A0 = (const f16x8*)(X + (size_t)(r1 + m) * HW + p0);
    const f16x8* A1 = (const f16x8*)(X + (size_t)(r1 + 16 + m) * HW + p0);
    const f16x8* B0 = (const f16x8*)(X + (size_t)(r2 + m) * HW + p0);
    const f16x8* B1 = (const f16x8*)(X + (size_t)(r2 + 16 + m) * HW + p0);
    f32x4 zero = {0, 0, 0, 0};
    f32x4 acc00 = zero, acc01 = zero, acc10 = zero, acc11 = zero;
#pragma unroll 4
    for (int it = 0; it < 16; ++it) {
        f16x8 a0 = A0[it * 4], a1 = A1[it * 4];
        f16x8 b0 = B0[it * 4], b1 = B1[it * 4];
        acc00 = __builtin_amdgcn_mfma_f32_16x16x32_f16(a0, b0, acc00, 0, 0, 0);
        acc01 = __builtin_amdgcn_mfma_f32_16x16x32_f16(a0, b1, acc01, 0, 0, 0);
        acc10 = __builtin_amdgcn_mfma_f32_16x16x32_f16(a1, b0, acc10, 0, 0, 0);
        acc11 = __builtin_amdgcn_mfma_f32_16x16x32_f16(a1, b1, acc11, 0, 0, 0);
    }
    float* dst = Pm2 + ((size_t)chunk * 6 + xb) * 65536;
#pragma unroll
    for (int r = 0; r < 4; ++r) {
        int row0 = (r1 + quad * 4 + r) * 256, row1 = (r1 + 16 + quad * 4 + r) * 256;
        dst[row0 + r2 + m] = acc00[r];
        dst[row0 + r2 + 16 + m] = acc01[r];
        dst[row1 + r2 + m] = acc10[r];
        dst[row1 + r2 + 16 + m] = acc11[r];
    }
}

// ---- combine M2 partials over 8 chunks ----
__global__ __launch_bounds__(256) void m2combine_kernel(const float* Pm2, float* M2) {
    size_t e = (size_t)blockIdx.x * 256 + threadIdx.x;   // 0 .. 6*65536-1
    float s = 0.f;
#pragma unroll
    for (int c = 0; c < 8; ++c) s += Pm2[(size_t)c * 6 * 65536 + e];
    M2[e] = s * (1.f / HW);
}

// ---------------- per-(x,b,o) affine params from stats (q pre-scaled by log2e) ----------------
__global__ __launch_bounds__(256) void stats_kernel(const float* M2, const float* mean,
        const float* W1, const float* W2, const float* W3,
        const float* g1, const float* g2, const float* g3,
        const float* b1, const float* b2, const float* b3, float2* afine) {
    int o = blockIdx.x; int xi = blockIdx.y; int b = blockIdx.z;
    int widx = o >> 5; int oc = o & 31;
    const float* Wp = (widx == 0 ? W1 : widx == 1 ? W2 : W3) + oc * CIN;
    const float* gp = (widx == 0 ? g1 : widx == 1 ? g2 : g3);
    const float* bp = (widx == 0 ? b1 : widx == 1 ? b2 : b3);
    int t = threadIdx.x;
    __shared__ float sW[256];
    __shared__ float red[256];
    sW[t] = Wp[t];
    __syncthreads();
    const float* m2row = M2 + ((size_t)(xi * 2 + b) * CIN + t) * CIN;
    float tv = 0.f;
    const f32x4* r4 = (const f32x4*)m2row;
#pragma unroll 4
    for (int k = 0; k < 64; ++k) {
        f32x4 mv = r4[k];
        const f32x4 wv = *(const f32x4*)&sW[k * 4];
        tv += mv[0] * wv[0] + mv[1] * wv[1] + mv[2] * wv[2] + mv[3] * wv[3];
    }
    red[t] = tv * sW[t]; __syncthreads();
    for (int k = 128; k; k >>= 1) { if (t < k) red[t] += red[t + k]; __syncthreads(); }
    float E2 = red[0]; __syncthreads();
    red[t] = sW[t] * mean[(xi * 2 + b) * CIN + t]; __syncthreads();
    for (int k = 128; k; k >>= 1) { if (t < k) red[t] += red[t + k]; __syncthreads(); }
    if (t == 0) {
        float mu = red[0];
        float var = E2 - mu * mu;
        float rsig = rsqrtf(var + 1e-5f);
        float scale = gp[oc] * rsig;
        float bias = bp[oc] - mu * scale;
        if (widx == 0) { scale *= L2E; bias *= L2E; }   // q carries log2e so S' = S*log2e
        afine[(xi * 2 + b) * 96 + o] = make_float2(scale, bias);
    }
}

// ---- conv + norm + relu: writes qT/kT (fp16), v (fp32 out), and row-norm maxima (atomics) ----
__global__ __launch_bounds__(256) void conv_kernel(const _Float16* xh, const _Float16* wh,
        const float2* afine, _Float16* qT, _Float16* kT, float* out,
        float* maxq, float* maxk) {
    int xi = blockIdx.y, b = blockIdx.z;
    const u16* xb = (const u16*)(xh + (size_t)(xi * 2 + b) * CIN * HW);
    int p0 = blockIdx.x * 64;
    __shared__ u16 lds[32 * 65 * 8];
    __shared__ float smq[4], smk[4];
    int t = threadIdx.x;
    {   // stage x[256][64] into LDS, transposed to 8-channel cells [cblk][f(p)][8c]
        int pc = t & 7, cg = t >> 3;
        u16x8 a[8];
#pragma unroll
        for (int r = 0; r < 8; ++r)
            a[r] = *(const u16x8*)(xb + (size_t)(cg * 8 + r) * HW + p0 + pc * 8);
#pragma unroll
        for (int i = 0; i < 8; ++i) {
            u16x8 d;
#pragma unroll
            for (int r = 0; r < 8; ++r) d[r] = a[r][i];
            int p = pc * 8 + i; int fp = p ^ (p >> 3);
            *(u16x8*)&lds[(cg * 65 + fp) * 8] = d;
        }
    }
    __syncthreads();
    int wv = t >> 6, L = t & 63, m = L & 15, quad = L >> 4;
    int pw0 = wv * 16;
    f16x8 af[8];
    {
        int p = pw0 + m; int fp = p ^ (p >> 3);
#pragma unroll
        for (int k = 0; k < 8; ++k)
            af[k] = *(const f16x8*)&lds[((k * 4 + quad) * 65 + fp) * 8];
    }
    int xb2 = xi * 2 + b;
    float sqq[4] = {0, 0, 0, 0}, sqk[4] = {0, 0, 0, 0};
    for (int ot = 0; ot < 6; ++ot) {
        int o0 = ot * 16; int widx = ot >> 1;
        int o_col = o0 + m;                         // global output channel 0..95
        f32x4 acc = {0, 0, 0, 0};
#pragma unroll
        for (int k = 0; k < 8; ++k) {
            f16x8 bfr = *(const f16x8*)(wh + (size_t)o_col * CIN + k * 32 + quad * 8);
            acc = __builtin_amdgcn_mfma_f32_16x16x32_f16(af[k], bfr, acc, 0, 0, 0);
        }
        float2 afv = afine[xb2 * 96 + o_col];
        f32x4 vals;
#pragma unroll
        for (int r = 0; r < 4; ++r) {
            float v = acc[r] * afv.x + afv.y;
            vals[r] = v > 0.f ? v : 0.f;
        }
        int prow = p0 + pw0 + quad * 4;
        if (widx < 2) {
            _Float16* dst = (widx == 0 ? qT : kT) + (size_t)xb2 * HW32;
            int cc = (o0 & 31) + m;
#pragma unroll
            for (int r = 0; r < 4; ++r)
                dst[(size_t)(prow + r) * 32 + cc] = (_Float16)vals[r];
            if (widx == 0) {
#pragma unroll
                for (int r = 0; r < 4; ++r) sqq[r] += vals[r] * vals[r];
            } else {
#pragma unroll
                for (int r = 0; r < 4; ++r) sqk[r] += vals[r] * vals[r];
            }
        } else {
            float* dst = out + (size_t)(5 + xi) * 262144 + (size_t)b * 131072 + (size_t)(o_col - 64) * HW + prow;
            *(f32x4*)dst = vals;    // fp32 output, 4 consecutive pixels
        }
    }
    // row-norm^2 reduce over 16 channel-lanes, then wave/block max, one atomic per block
#pragma unroll
    for (int msk = 1; msk <= 8; msk <<= 1) {
#pragma unroll
        for (int r = 0; r < 4; ++r) {
            sqq[r] += __shfl_xor(sqq[r], msk);
            sqk[r] += __shfl_xor(sqk[r], msk);
        }
    }
    float nq = fmaxf(fmaxf(sqq[0], sqq[1]), fmaxf(sqq[2], sqq[3]));
    float nk = fmaxf(fmaxf(sqk[0], sqk[1]), fmaxf(sqk[2], sqk[3]));
    nq = fmaxf(nq, __shfl_xor(nq, 16)); nq = fmaxf(nq, __shfl_xor(nq, 32));
    nk = fmaxf(nk, __shfl_xor(nk, 16)); nk = fmaxf(nk, __shfl_xor(nk, 32));
    if (L == 0) { smq[wv] = nq; smk[wv] = nk; }
    __syncthreads();
    if (t == 0) {
        float bq = fmaxf(fmaxf(smq[0], smq[1]), fmaxf(smq[2], smq[3]));
        float bk = fmaxf(fmaxf(smk[0], smk[1]), fmaxf(smk[2], smk[3]));
        atomicMax((unsigned*)&maxq[xb2], __float_as_uint(bq));   // nonneg floats: uint order == float order
        atomicMax((unsigned*)&maxk[xb2], __float_as_uint(bk));
    }
}

// ---- Z-sweep (single pass, constant shift): per-chunk partial Z sums ----
__global__ __launch_bounds__(256) void zsweep_kernel(const _Float16* qT, const _Float16* kT,
        const float* maxq, const float* maxk, float* Pz) {
    const int qxA[5] = {0, 1, 1, 2, 0};   // mats: A12 A21 A23 A32 A13
    const int kxA[5] = {1, 0, 2, 1, 2};
    int mat = blockIdx.y, b = blockIdx.z;
    const _Float16* qb = qT + (size_t)(qxA[mat] * 2 + b) * HW32;
    const _Float16* kb = kT + (size_t)(kxA[mat] * 2 + b) * HW32;
    float Cg = sqrtf(maxq[qxA[mat] * 2 + b]) * sqrtf(maxk[kxA[mat] * 2 + b]);  // log2-domain (q scaled by L2E)
    int bx = blockIdx.x;                 // 16 qblk x 16 jc
    int jc = bx & 15, qblk = bx >> 4;
    int t = threadIdx.x; int wv = t >> 6; int L = t & 63; int m = L & 15; int quad = L >> 4;
    int i0 = qblk * 256 + wv * 64;       // wave covers 64 q rows (4 tiles)
    f16x8 a[4];
#pragma unroll
    for (int tt = 0; tt < 4; ++tt)
        a[tt] = *(const f16x8*)(qb + (size_t)(i0 + tt * 16 + m) * 32 + quad * 8);
    const f16x8* kp = (const f16x8*)(kb + m * 32 + quad * 8) + (size_t)jc * (16 * 64);
    f32x4 negC = {-Cg, -Cg, -Cg, -Cg};
    f32x4 zero = {0.f, 0.f, 0.f, 0.f};
    f32x4 z[4] = {zero, zero, zero, zero};
#pragma unroll 4
    for (int j = 0; j < 16; ++j) {
        f16x8 bf = kp[j * 64];
#pragma unroll
        for (int tt = 0; tt < 4; ++tt) {
            f32x4 d = __builtin_amdgcn_mfma_f32_16x16x32_f16(a[tt], bf, negC, 0, 0, 0);
            f32x4 e = {fexp2(d[0]), fexp2(d[1]), fexp2(d[2]), fexp2(d[3])};
            z[tt] = z[tt] + e;           // vector add -> v_pk_add_f32
        }
    }
#pragma unroll
    for (int tt = 0; tt < 4; ++tt)
#pragma unroll
        for (int msk = 1; msk <= 8; msk <<= 1) {
            z[tt][0] += __shfl_xor(z[tt][0], msk); z[tt][1] += __shfl_xor(z[tt][1], msk);
            z[tt][2] += __shfl_xor(z[tt][2], msk); z[tt][3] += __shfl_xor(z[tt][3], msk);
        }
    if (m == 0) {
        int mb = mat * 2 + b;
#pragma unroll
        for (int tt = 0; tt < 4; ++tt) {
            int row = i0 + tt * 16 + quad * 4;
#pragma unroll
            for (int r = 0; r < 4; ++r)
                Pz[((size_t)mb * 16 + jc) * HW + row + r] = z[tt][r];
        }
    }
}

// ---- combine zsweep partials (shared shift): Z = sum, R = 1/Z ----
__global__ __launch_bounds__(256) void zcombine_kernel(const float* Pz, float* R, float2* Wa) {
    int mb = blockIdx.y;                 // 0..9 = mat*2+b
    int r = blockIdx.x * 256 + threadIdx.x;
    float Z = 0.f;
#pragma unroll
    for (int c = 0; c < 16; ++c) Z += Pz[((size_t)mb * 16 + c) * HW + r];
    float rz = 1.0f / Z;
    size_t idx = (size_t)mb * HW + r;
    R[idx] = rz;
    if (mb < 2 || mb >= 8) Wa[idx] = make_float2(rz, 0.f);   // weights for A12 / A13 sweeps
}

// ---- pass2, i-chunked, 4 j-tiles/wave, constant shift: partial (s1,s2)[ic][b][j] ----
struct PCfg {
    const _Float16* qb; const _Float16* kb;   // bases covering 2 batches
    const float* mq; const float* mk;         // per-batch shift factors (squared norms)
    const float2* wt;                         // [2][HW] weights per i
    float2* Pp;                               // [(ic*2+b)*HW + j]
    int nit;                                  // i-iters per chunk (chunk = nit*16 rows)
    int dual;                                 // 0: only w.x used (A-pair), 1: both
};

__global__ __launch_bounds__(256) void pass2p_kernel(PCfg c0, PCfg c1) {
    PCfg c = (blockIdx.y == 0) ? c0 : c1;
    int b = blockIdx.z;
    int bx = blockIdx.x; int jb = bx & 15; int ic = bx >> 4;
    const _Float16* qb = c.qb + (size_t)b * HW32;
    const _Float16* kb = c.kb + (size_t)b * HW32;
    const f32x2* wt = (const f32x2*)(c.wt + (size_t)b * HW);
    float Cg = sqrtf(c.mq[b]) * sqrtf(c.mk[b]);
    int t = threadIdx.x; int wv = t >> 6; int L = t & 63; int m = L & 15; int quad = L >> 4;
    int j0 = jb * 256 + wv * 64;         // wave covers 64 j columns (4 tiles)
    f16x8 bf[4];
#pragma unroll
    for (int tt = 0; tt < 4; ++tt)
        bf[tt] = *(const f16x8*)(kb + (size_t)(j0 + tt * 16 + m) * 32 + quad * 8);
    f32x4 negC = {-Cg, -Cg, -Cg, -Cg};
    f32x2 acc[4] = {{0, 0}, {0, 0}, {0, 0}, {0, 0}};
    int ibase = ic * (c.nit * 16);
    if (c.dual) {
#pragma unroll 4
        for (int it = 0; it < c.nit; ++it) {
            int i0 = ibase + it * 16;
            f16x8 av = *(const f16x8*)(qb + (size_t)(i0 + m) * 32 + quad * 8);
            const f32x2* wr = wt + i0 + quad * 4;
            f32x2 w0 = wr[0], w1 = wr[1], w2 = wr[2], w3 = wr[3];
#pragma unroll
            for (int tt = 0; tt < 4; ++tt) {
                f32x4 d = __builtin_amdgcn_mfma_f32_16x16x32_f16(av, bf[tt], negC, 0, 0, 0);
                float e0 = fexp2(d[0]), e1 = fexp2(d[1]), e2 = fexp2(d[2]), e3 = fexp2(d[3]);
                acc[tt] += (f32x2){e0, e0} * w0;   // v_pk_fma_f32
                acc[tt] += (f32x2){e1, e1} * w1;
                acc[tt] += (f32x2){e2, e2} * w2;
                acc[tt] += (f32x2){e3, e3} * w3;
            }
        }
    } else {
#pragma unroll 4
        for (int it = 0; it < c.nit; ++it) {
            int i0 = ibase + it * 16;
            f16x8 av = *(const f16x8*)(qb + (size_t)(i0 + m) * 32 + quad * 8);
            const f32x2* wr = wt + i0 + quad * 4;
            float w0 = wr[0][0], w1 = wr[1][0], w2 = wr[2][0], w3 = wr[3][0];
#pragma unroll
            for (int tt = 0; tt < 4; ++tt) {
                f32x4 d = __builtin_amdgcn_mfma_f32_16x16x32_f16(av, bf[tt], negC, 0, 0, 0);
                float e0 = fexp2(d[0]), e1 = fexp2(d[1]), e2 = fexp2(d[2]), e3 = fexp2(d[3]);
                acc[tt][0] += e0 * w0 + e1 * w1 + e2 * w2 + e3 * w3;
            }
        }
    }
#pragma unroll
    for (int tt = 0; tt < 4; ++tt) {
        acc[tt][0] += __shfl_xor(acc[tt][0], 16); acc[tt][0] += __shfl_xor(acc[tt][0], 32);
        acc[tt][1] += __shfl_xor(acc[tt][1], 16); acc[tt][1] += __shfl_xor(acc[tt][1], 32);
    }
    if (quad == 0) {
        float2* dst = c.Pp + ((size_t)ic * 2 + b) * HW;
#pragma unroll
        for (int tt = 0; tt < 4; ++tt)
            dst[j0 + tt * 16 + m] = make_float2(acc[tt][0], acc[tt][1]);
    }
}

// ---- prepA: combine A12/A13 partials -> c12, c13(p3b); build A23 weights ----
__global__ __launch_bounds__(256) void prepA_kernel(const float2* PpA, const float* R,
        float* c12, float* c13, float2* Wa2) {
    int b = blockIdx.y; int j = blockIdx.x * 256 + threadIdx.x;
    float s12 = 0.f, s13 = 0.f;
    for (int ic = 0; ic < 16; ++ic) {
        s12 += PpA[((size_t)ic * 2 + b) * HW + j].x;
        s13 += PpA[((size_t)(16 + ic) * 2 + b) * HW + j].x;
    }
    c12[(size_t)b * HW + j] = s12; c13[(size_t)b * HW + j] = s13;
    float rn = R[((size_t)(2 * 2 + b)) * HW + j];     // 1/Z for A23
    Wa2[(size_t)b * HW + j] = make_float2(rn, s12 * rn);
}

// ---- prep: combine IC partials -> o1,o2; build next weights ----
__global__ __launch_bounds__(256) void prep_kernel(const float2* Pp, const float* Rn,
        const float* aux, float* o1, float* o2, float2* Wn, int IC, int mode) {
    int b = blockIdx.y; int j = blockIdx.x * 256 + threadIdx.x;
    float s1 = 0.f, s2 = 0.f;
    for (int ic = 0; ic < IC; ++ic) {
        float2 p = Pp[((size_t)ic * 2 + b) * HW + j];
        s1 += p.x; s2 += p.y;
    }
    if (o1) o1[(size_t)b * HW + j] = s1;
    if (o2) o2[(size_t)b * HW + j] = s2;
    if (Wn) {
        float rn = Rn[(size_t)b * HW + j];
        float2 w = (mode == 0) ? make_float2(s1 * rn, s2 * rn)
                               : make_float2(s2 * rn, aux[(size_t)b * HW + j] * rn);
        Wn[(size_t)b * HW + j] = w;
    }
}

// ---- broadcast 5 [b,hw] vectors to fp32 [b,32,hw] outputs ----
__global__ __launch_bounds__(256) void bcast_kernel(const float* vecs, float* out) {
    int bx = blockIdx.x;              // 0..319
    int s = bx >> 6; int rem = bx & 63; int b = rem >> 5; int c = rem & 31;
    const float* src = vecs + ((size_t)s * 2 + b) * HW;   // slots 0..4 in output order
    float* dst = out + ((size_t)(s * 2 + b) * 32 + c) * HW;
    int t = threadIdx.x;
#pragma unroll
    for (int k = 0; k < 4; ++k)
        ((f32x4*)dst)[k * 256 + t] = ((const f32x4*)src)[k * 256 + t];
}

extern "C" void kernel_launch(void* const* d_in, const int* in_sizes, int n_in,
                              void* d_out, int out_size, void* d_ws, size_t ws_size,
                              hipStream_t stream) {
    (void)in_sizes; (void)n_in; (void)out_size; (void)ws_size;
    const float* x1 = (const float*)d_in[0];
    const float* x2 = (const float*)d_in[1];
    const float* x3 = (const float*)d_in[2];
    const float* W1 = (const float*)d_in[3];
    const float* g1 = (const float*)d_in[4];
    const float* b1 = (const float*)d_in[5];
    const float* W2 = (const float*)d_in[6];
    const float* g2 = (const float*)d_in[7];
    const float* b2 = (const float*)d_in[8];
    const float* W3 = (const float*)d_in[9];
    const float* g3 = (const float*)d_in[10];
    const float* b3 = (const float*)d_in[11];
    float* out = (float*)d_out;      // reference outputs are float32

    char* w = (char*)d_ws;
    _Float16* xh    = (_Float16*)(w);                    // 12,582,912
    _Float16* wh    = (_Float16*)(w + 12582912);         //     49,152
    float*    mean  = (float*)(w + 12632064);            //      6,144
    float*    M2    = (float*)(w + 12638208);            //  1,572,864
    float2*   afine = (float2*)(w + 14211072);           //      4,608
    _Float16* qT    = (_Float16*)(w + 14215680);         //  1,572,864
    _Float16* kT    = (_Float16*)(w + 15788544);         //  1,572,864
    float*    R     = (float*)(w + 17361408);            //    163,840
    float*    maxq  = (float*)(w + 17525248);            //         64 (squared norms)
    float*    maxk  = (float*)(w + 17525312);            //         64
    float2*   Wa    = (float2*)(w + 17689088);           //    327,680
    float*    vecs  = (float*)(w + 18016768);            //    196,608 (6 slots x 2 x HW)
    float*    Pz    = (float*)(w + 18213376);            //  2,621,440
    float2*   PpA   = (float2*)(w + 23456256);           //  2,097,152
    float2*   PpB   = (float2*)(w + 25553408);           //  2,097,152
    float2*   PpC   = (float2*)(w + 27650560);           //  2,097,152
    float2*   PpD   = (float2*)(w + 29747712);           //  2,097,152
    // Pm2 overlays Pz/PpA/PpB/PpC (disjoint lifetime: consumed by m2combine before zsweep runs)
    float*    Pm2   = (float*)(w + 18213376);            // 12,582,912 (8 chunks x 6 x 256x256 f32)

    float* v_p1a = vecs + 0 * 2 * HW;
    float* v_p1b = vecs + 1 * 2 * HW;
    float* v_p2  = vecs + 2 * 2 * HW;
    float* v_p3a = vecs + 3 * 2 * HW;
    float* v_p3b = vecs + 4 * 2 * HW;   // c13
    float* v_c12 = vecs + 5 * 2 * HW;

    hipLaunchKernelGGL(convert_kernel, dim3(1542), dim3(256), 0, stream,
                       x1, x2, x3, W1, W2, W3, xh, wh, mean, maxq, maxk);
    hipLaunchKernelGGL(m2_kernel, dim3(128, 3, 2), dim3(256), 0, stream, xh, Pm2);
    hipLaunchKernelGGL(m2combine_kernel, dim3(1536), dim3(256), 0, stream, Pm2, M2);
    hipLaunchKernelGGL(stats_kernel, dim3(96, 3, 2), dim3(256), 0, stream,
                       M2, mean, W1, W2, W3, g1, g2, g3, b1, b2, b3, afine);
    hipLaunchKernelGGL(conv_kernel, dim3(64, 3, 2), dim3(256), 0, stream,
                       xh, wh, afine, qT, kT, out, maxq, maxk);
    hipLaunchKernelGGL(zsweep_kernel, dim3(256, 5, 2), dim3(256), 0, stream, qT, kT, maxq, maxk, Pz);
    hipLaunchKernelGGL(zcombine_kernel, dim3(16, 10), dim3(256), 0, stream, Pz, R, Wa);

    // mats: 0:A12(q1,k2) 1:A21(q2,k1) 2:A23(q2,k3) 3:A32(q3,k2) 4:A13(q1,k3)
    // A-pair: A12 and A13 with w = {1/Z, 0}; IC=16 (nit=16), single-weight
    PCfg cA0 = { qT + 0 * 2 * HW32, kT + 1 * 2 * HW32, maxq + 0, maxk + 2, Wa + 0 * 2 * HW, PpA,               16, 0 };
    PCfg cA1 = { qT + 0 * 2 * HW32, kT + 2 * 2 * HW32, maxq + 0, maxk + 4, Wa + 4 * 2 * HW, PpA + 16 * 2 * HW, 16, 0 };
    hipLaunchKernelGGL(pass2p_kernel, dim3(256, 2, 2), dim3(256), 0, stream, cA0, cA1);
    hipLaunchKernelGGL(prepA_kernel, dim3(16, 2), dim3(256), 0, stream,
                       PpA, R, v_c12, v_p3b, Wa + 2 * 2 * HW);

    // B: A23 sweep (q2,k3), w = {rn23, c12*rn23} -> o1=c23, o2=u1(p3a); IC=32 (nit=8)
    PCfg cB = { qT + 1 * 2 * HW32, kT + 2 * 2 * HW32, maxq + 2, maxk + 4, Wa + 2 * 2 * HW, PpB, 8, 1 };
    hipLaunchKernelGGL(pass2p_kernel, dim3(512, 1, 2), dim3(256), 0, stream, cB, cB);
    hipLaunchKernelGGL(prep_kernel, dim3(16, 2), dim3(256), 0, stream,
                       PpB, R + 3 * 2 * HW, (const float*)nullptr,
                       (float*)nullptr, v_p3a, Wa + 3 * 2 * HW, 32, 0);

    // C: A32 sweep (q3,k2), w = {c23*rn32, u1*rn32} -> o1=p2, o2=u2; IC=32
    PCfg cC = { qT + 2 * 2 * HW32, kT + 1 * 2 * HW32, maxq + 4, maxk + 2, Wa + 3 * 2 * HW, PpC, 8, 1 };
    hipLaunchKernelGGL(pass2p_kernel, dim3(512, 1, 2), dim3(256), 0, stream, cC, cC);
    hipLaunchKernelGGL(prep_kernel, dim3(16, 2), dim3(256), 0, stream,
                       PpC, R + 1 * 2 * HW, v_c12,
                       v_p2, (float*)nullptr, Wa + 1 * 2 * HW, 32, 1);

    // D: A21 sweep (q2,k1), w = {u2*rn21, c12*rn21} -> o1=p1a, o2=p1b; IC=32
    PCfg cD = { qT + 1 * 2 * HW32, kT + 0 * 2 * HW32, maxq + 2, maxk + 0, Wa + 1 * 2 * HW, PpD, 8, 1 };
    hipLaunchKernelGGL(pass2p_kernel, dim3(512, 1, 2), dim3(256), 0, stream, cD, cD);
    hipLaunchKernelGGL(prep_kernel, dim3(16, 2), dim3(256), 0, stream,
                       PpD, (const float*)nullptr, (const float*)nullptr,
                       v_p1a, v_p1b, (float2*)nullptr, 32, 0);

    hipLaunchKernelGGL(bcast_kernel, dim3(320), dim3(256), 0, stream, vecs, out);
}